// Round 1
// baseline (5600.330 us; speedup 1.0000x reference)
//
#include <hip/hip_runtime.h>
#include <math.h>

// Problem constants (V,E,H,K,T,B) = (32000, 512, 512, 32, 256, 64)
#define T_STEPS 256
#define BATCH   64
#define HID     512
#define KTAGS   32
#define NEGV    -100000.0f
#define START_TAG 30
#define END_TAG   31

#define NBLK      256
#define SPIN_LIM  (1 << 26)
#define LAYER_DONE 300u

typedef __attribute__((ext_vector_type(8))) short short8;
typedef __attribute__((ext_vector_type(4))) float f32x4;

union V16 { uint4 u; short8 s; };
union HQ  { unsigned long long q[2]; short8 s; };

static __device__ __forceinline__ unsigned short f2b(float f) {
    unsigned u = __float_as_uint(f);
    return (unsigned short)((u + 0x7fffu + ((u >> 16) & 1u)) >> 16);
}
static __device__ __forceinline__ float b2f(unsigned short us) {
    return __uint_as_float(((unsigned)us) << 16);
}

// ---------------------------------------------------------------------------
// Init: zero flag region (agent-scope stores — step kernel reads flags via
// agent atomics which bypass local L2) + d_out.
// ---------------------------------------------------------------------------
__global__ __launch_bounds__(256) void init_zero(unsigned int* __restrict__ flags,
                                                 float* __restrict__ out)
{
    int i = blockIdx.x * 256 + threadIdx.x;
    if (i < 1024)
        __hip_atomic_store(flags + i, 0u, __ATOMIC_RELAXED, __HIP_MEMORY_SCOPE_AGENT);
    if (i == 0)
        __hip_atomic_store(out, 0.0f, __ATOMIC_RELAXED, __HIP_MEMORY_SCOPE_AGENT);
}

// ---------------------------------------------------------------------------
// embed fp32 -> bf16 (one-time, 16.4M elements)
// ---------------------------------------------------------------------------
__global__ __launch_bounds__(256) void convert_embed(const float* __restrict__ src,
                                                     unsigned short* __restrict__ dst)
{
    long long i = ((long long)blockIdx.x * 256 + threadIdx.x) * 4;
    if (i >= (long long)32000 * 512) return;
    float4 v = *(const float4*)(src + i);
    ushort4 o;
    o.x = f2b(v.x); o.y = f2b(v.y); o.z = f2b(v.z); o.w = f2b(v.w);
    *(ushort4*)(dst + i) = o;
}

// ---------------------------------------------------------------------------
// Pack Wih|Whh (fp32) into bf16 MFMA B-fragment stream.
// Stream: [d][nt(128)][kt(KT=xKt+16)][lane(64)][j(8)], where the 16 B-frag
// cols of block nt are {g*512 + nt*4 + j2 : g=0..3, j2=0..3} (c = g*4+j2 =
// lane&15), and k_local = (lane>>4)*8 + j.  kt<xKt -> Wih, else Whh.
// ---------------------------------------------------------------------------
__global__ __launch_bounds__(256) void pack_w(const float* __restrict__ wih,
                                              const float* __restrict__ whh,
                                              int xK,
                                              unsigned short* __restrict__ wpack)
{
    const int xKt = xK >> 5, KT = xKt + 16;
    long long t = (long long)blockIdx.x * 256 + threadIdx.x;
    if (t >= (long long)2 * 128 * KT * 64) return;
    int lane = (int)(t & 63);
    long long rest = t >> 6;
    int kt = (int)(rest % KT); rest /= KT;
    int nt = (int)(rest % 128);
    int d  = (int)(rest / 128);
    int c = lane & 15, q = lane >> 4;
    int r = (c >> 2) * 512 + nt * 4 + (c & 3);
    const float* src;
    if (kt < xKt) src = wih + ((long long)d * 2048 * xK + (long long)r * xK + kt * 32 + q * 8);
    else          src = whh + ((long long)d * 2048 * 512 + (long long)r * 512 + (kt - xKt) * 32 + q * 8);
    float4 v0 = *(const float4*)src;
    float4 v1 = *(const float4*)(src + 4);
    unsigned short o[8] = { f2b(v0.x), f2b(v0.y), f2b(v0.z), f2b(v0.w),
                            f2b(v1.x), f2b(v1.y), f2b(v1.z), f2b(v1.w) };
    *(uint4*)(wpack + t * 8) = *(const uint4*)o;
}

// ---------------------------------------------------------------------------
// One BiLSTM layer, templated on input width so all weight/B-frag arrays are
// statically indexed (registers, not scratch).
//
// Sync redesign vs previous version:
//  - per-BLOCK u16 step counters (flg[nt] = completed steps), plain relaxed
//    agent stores -> NO same-address RMW fan-in chain.
//  - consumers: 32 threads poll one u64 each (4 flags) in parallel.
//  - weight B-frags (bvX, bvH) hoisted out of the step loop entirely.
//  - all 32 recurrent h-loads issued as one burst before the MFMA chain.
//  - h publish packs the gj-quad via shfl_xor (no hsh LDS, one fewer barrier).
// Ordering: h stores drained with wave-local s_waitcnt vmcnt(0), then
// __syncthreads, then tid0 stores the flag — same ordering discipline the
// previous (passing) kernel used for its flag add.
// ---------------------------------------------------------------------------
template<int XK>
static __device__ __forceinline__ void lstm_layer(
    const int d, const int nt, const int tid,
    const int* __restrict__ tokens,
    const unsigned short* __restrict__ embB,
    const unsigned short* __restrict__ wp,     // this block's packed weights
    const float* __restrict__ bia,
    const unsigned short* __restrict__ hs_in,  // layer-1 input rows (bf16 [T*64][1024])
    unsigned short* __restrict__ hso,
    unsigned long long* __restrict__ hbuf64,
    unsigned short* __restrict__ flg,          // this (l,d) region: 128 u16
    int* __restrict__ tok_s,
    float (* __restrict__ Gred)[64][17])
{
    constexpr bool L0  = (XK == 512);
    constexpr int  xKt = XK >> 5;
    constexpr int  nX  = xKt >> 2;             // X-phase kts per wave

    const int w = tid >> 6, lane = tid & 63;
    const int lm = lane & 15, q = lane >> 4;
    const int gm = tid >> 2,  gj = tid & 3;    // gate-phase cell (batch, hcol-off)

    // ---- step-invariant: weight fragments live in registers for the layer --
    uint4 bvX[nX], bvH[4];
    #pragma unroll
    for (int i = 0; i < nX; ++i)
        bvX[i] = *(const uint4*)(wp + (long long)(w * nX + i) * 512 + lane * 8);
    #pragma unroll
    for (int i = 0; i < 4; ++i)
        bvH[i] = *(const uint4*)(wp + (long long)(xKt + w * 4 + i) * 512 + lane * 8);

    float breg[4];
    #pragma unroll
    for (int g = 0; g < 4; ++g) breg[g] = bia[g * 512 + nt * 4 + gj];
    float creg = 0.0f;
    bool  dead = false;

    for (int s = 0; s < T_STEPS; ++s) {
        const int tt = d ? (T_STEPS - 1 - s) : s;

        f32x4 acc[4];
        #pragma unroll
        for (int mt = 0; mt < 4; ++mt) acc[mt] = (f32x4)0.0f;

        if constexpr (L0) {
            if (tid < 64) tok_s[tid] = tokens[tt * BATCH + tid];
            __syncthreads();
        }

        const unsigned short* xr[4];
        #pragma unroll
        for (int mt = 0; mt < 4; ++mt) {
            int m = mt * 16 + lm;
            if constexpr (L0) xr[mt] = embB + (long long)tok_s[m] * 512;
            else              xr[mt] = hs_in + ((long long)tt * 64 + m) * 1024;
        }

        // ---------------- X phase (no h dependency, overlaps the wait) ------
        #pragma unroll
        for (int i = 0; i < nX; ++i) {
            const int kt = w * nX + i;
            V16 bv; bv.u = bvX[i];
            #pragma unroll
            for (int mt = 0; mt < 4; ++mt) {
                V16 av; av.u = *(const uint4*)(xr[mt] + kt * 32 + q * 8);
                acc[mt] = __builtin_amdgcn_mfma_f32_16x16x32_bf16(av.s, bv.s, acc[mt], 0, 0, 0);
            }
        }

        // ---------------- wait h(s-1): parallel poll of per-block flags -----
        if (s > 0) {
            if (tid < 32 && !dead) {
                const unsigned long long* f64 = (const unsigned long long*)flg;
                int n = 0;
                for (;;) {
                    unsigned long long v = __hip_atomic_load(f64 + tid, __ATOMIC_RELAXED,
                                                             __HIP_MEMORY_SCOPE_AGENT);
                    if ( (unsigned)( v        & 0xFFFF) >= (unsigned)s &&
                         (unsigned)((v >> 16) & 0xFFFF) >= (unsigned)s &&
                         (unsigned)((v >> 32) & 0xFFFF) >= (unsigned)s &&
                         (unsigned)( v >> 48          ) >= (unsigned)s ) break;
                    __builtin_amdgcn_s_sleep(1);
                    if (++n > SPIN_LIM) { dead = true; break; }
                }
            }
            __syncthreads();

            // ---------------- recurrent phase: burst-load, then MFMA --------
            const unsigned long long* hb =
                hbuf64 + ((long long)(((s - 1) & 1) * 2 + d) * 64 * 512) / 4;
            HQ hq[4][4];
            #pragma unroll
            for (int i = 0; i < 4; ++i) {
                const int kth = w * 4 + i;
                #pragma unroll
                for (int mt = 0; mt < 4; ++mt) {
                    const int m = mt * 16 + lm;
                    const long long o = ((long long)m * 512 + kth * 32 + q * 8) >> 2;
                    hq[i][mt].q[0] = __hip_atomic_load(hb + o,     __ATOMIC_RELAXED, __HIP_MEMORY_SCOPE_AGENT);
                    hq[i][mt].q[1] = __hip_atomic_load(hb + o + 1, __ATOMIC_RELAXED, __HIP_MEMORY_SCOPE_AGENT);
                }
            }
            #pragma unroll
            for (int i = 0; i < 4; ++i) {
                V16 bv; bv.u = bvH[i];
                #pragma unroll
                for (int mt = 0; mt < 4; ++mt)
                    acc[mt] = __builtin_amdgcn_mfma_f32_16x16x32_bf16(hq[i][mt].s, bv.s, acc[mt], 0, 0, 0);
            }
        }

        // ---------------- K-reduce across waves + gates ---------------------
        #pragma unroll
        for (int mt = 0; mt < 4; ++mt)
            #pragma unroll
            for (int r = 0; r < 4; ++r)
                Gred[w][mt * 16 + q * 4 + r][lm] = acc[mt][r];
        __syncthreads();

        float vg[4];
        #pragma unroll
        for (int g = 0; g < 4; ++g) {
            float v = breg[g];
            #pragma unroll
            for (int ww = 0; ww < 4; ++ww) v += Gred[ww][gm][g * 4 + gj];
            vg[g] = v;
        }
        const float si = 1.0f / (1.0f + __expf(-vg[0]));
        const float sf = 1.0f / (1.0f + __expf(-vg[1]));
        const float so = 1.0f / (1.0f + __expf(-vg[3]));
        const float cn = sf * creg + si * tanhf(vg[2]);
        const float hn = so * tanhf(cn);
        creg = cn;

        // ---------------- publish h: shfl-pack gj-quad into one u64 ---------
        unsigned pv = (unsigned)f2b(hn);
        unsigned pp = pv | (__shfl_xor(pv, 1) << 16);
        unsigned long long hv = (unsigned long long)pp
                              | ((unsigned long long)__shfl_xor(pp, 2) << 32);
        if (gj == 0) {
            unsigned long long* dst =
                hbuf64 + ((long long)((s & 1) * 2 + d) * 64 * 512
                          + (long long)gm * 512 + nt * 4) / 4;
            __hip_atomic_store(dst, hv, __ATOMIC_RELAXED, __HIP_MEMORY_SCOPE_AGENT);
            *(unsigned long long*)(hso + ((long long)tt * 64 + gm) * 1024 + d * 512 + nt * 4) = hv;
        }
        asm volatile("s_waitcnt vmcnt(0)" ::: "memory");
        __syncthreads();
        if (tid == 0)
            __hip_atomic_store(flg + nt, (unsigned short)(s + 1),
                               __ATOMIC_RELAXED, __HIP_MEMORY_SCOPE_AGENT);
    }
}

// ---------------------------------------------------------------------------
// Persistent BiLSTM, MFMA edition. 256 blocks x 256 thr; d=bid>>7; block owns
// 4 h-cols (nt*4..+3) => 16 gate cols. Per-(l,d) flag region = 128 u16
// (per-block step counters). Layer barrier: threadfence (wb hs0) -> store
// LAYER_DONE into own flag -> poll both l=0 regions -> threadfence (inv).
// ---------------------------------------------------------------------------
__global__ __launch_bounds__(256, 1) void lstm_mfma(
    const int* __restrict__ tokens,
    const unsigned short* __restrict__ embB,
    const unsigned short* __restrict__ wp0,
    const unsigned short* __restrict__ wp1,
    const float* __restrict__ bb0, const float* __restrict__ bb1,
    unsigned short* __restrict__ hs0,
    unsigned short* __restrict__ hs1,
    unsigned long long* __restrict__ hbuf64,
    unsigned short* __restrict__ flags16)
{
    __shared__ int   tok_s[64];
    __shared__ float Gred[4][64][17];

    const int bid = blockIdx.x;
    const int d   = bid >> 7;
    const int nt  = bid & 127;
    const int tid = threadIdx.x;

    lstm_layer<512>(d, nt, tid, tokens, embB,
                    wp0 + (long long)(d * 128 + nt) * 32 * 512,   // KT=32
                    bb0 + (long long)d * 2048,
                    (const unsigned short*)nullptr, hs0, hbuf64,
                    flags16 + d * 128, tok_s, Gred);

    // ------------- layer boundary: publish hs0 for cached L1 reads ----------
    __threadfence();                        // wb dirty hs0 out of local L2
    __syncthreads();
    if (tid == 0)
        __hip_atomic_store(flags16 + d * 128 + nt, (unsigned short)LAYER_DONE,
                           __ATOMIC_RELAXED, __HIP_MEMORY_SCOPE_AGENT);
    if (tid < 64) {                         // poll both l=0 regions (256 u16)
        const unsigned long long* f64 = (const unsigned long long*)flags16;
        int n = 0;
        for (;;) {
            unsigned long long v = __hip_atomic_load(f64 + tid, __ATOMIC_RELAXED,
                                                     __HIP_MEMORY_SCOPE_AGENT);
            if ( (unsigned)( v        & 0xFFFF) >= LAYER_DONE &&
                 (unsigned)((v >> 16) & 0xFFFF) >= LAYER_DONE &&
                 (unsigned)((v >> 32) & 0xFFFF) >= LAYER_DONE &&
                 (unsigned)( v >> 48          ) >= LAYER_DONE ) break;
            __builtin_amdgcn_s_sleep(1);
            if (++n > SPIN_LIM) break;
        }
    }
    __syncthreads();
    __threadfence();                        // inv stale lines before cached reads

    lstm_layer<1024>(d, nt, tid, tokens, embB,
                     wp1 + (long long)(d * 128 + nt) * 48 * 512,  // KT=48
                     bb1 + (long long)d * 2048,
                     hs0, hs1, hbuf64,
                     flags16 + (2 + d) * 128, tok_s, Gred);
}

// ---------------------------------------------------------------------------
// feats = hs1(bf16) @ lin_w^T + lin_b   (64-row tiles, N=32)
// ---------------------------------------------------------------------------
__global__ __launch_bounds__(256) void gemm_feats(
    const unsigned short* __restrict__ A,      // [M][1024] bf16
    const float* __restrict__ W,               // [32][1024]
    const float* __restrict__ bias,
    float* __restrict__ C,
    int M, int N, int K)
{
    __shared__ __align__(16) float As[64][34];
    __shared__ __align__(16) float Ws[32][68];

    const int m0 = blockIdx.y * 64;
    const int tid = threadIdx.x;
    const int tr = tid >> 4;
    const int tc = tid & 15;

    float acc[4][4];
    #pragma unroll
    for (int i = 0; i < 4; ++i)
        #pragma unroll
        for (int j = 0; j < 4; ++j) acc[i][j] = 0.0f;

    for (int k0 = 0; k0 < K; k0 += 32) {
        {   // A tile: 64 rows x 32 k (bf16 -> f32)
            int row = tid >> 2, g8 = tid & 3;
            uint4 v = *(const uint4*)(A + ((long long)(m0 + row)) * 1024 + k0 + g8 * 8);
            const unsigned short* pv = (const unsigned short*)&v;
            #pragma unroll
            for (int e = 0; e < 8; ++e) As[row][g8 * 8 + e] = b2f(pv[e]);
        }
        {   // W tile: 32 rows x 32 k, transposed
            int row = tid >> 3, q2 = tid & 7;
            float4 v = *(const float4*)(W + (long long)row * K + k0 + 4 * q2);
            Ws[4*q2+0][row] = v.x; Ws[4*q2+1][row] = v.y;
            Ws[4*q2+2][row] = v.z; Ws[4*q2+3][row] = v.w;
        }
        __syncthreads();
        #pragma unroll 8
        for (int kk = 0; kk < 32; ++kk) {
            float a0 = As[4*tr+0][kk], a1 = As[4*tr+1][kk];
            float a2 = As[4*tr+2][kk], a3 = As[4*tr+3][kk];
            float4 wv = *(const float4*)&Ws[kk][4*tc];
            acc[0][0] += a0*wv.x; acc[0][1] += a0*wv.y; acc[0][2] += a0*wv.z; acc[0][3] += a0*wv.w;
            acc[1][0] += a1*wv.x; acc[1][1] += a1*wv.y; acc[1][2] += a1*wv.z; acc[1][3] += a1*wv.w;
            acc[2][0] += a2*wv.x; acc[2][1] += a2*wv.y; acc[2][2] += a2*wv.z; acc[2][3] += a2*wv.w;
            acc[3][0] += a3*wv.x; acc[3][1] += a3*wv.y; acc[3][2] += a3*wv.z; acc[3][3] += a3*wv.w;
        }
        __syncthreads();
    }
    #pragma unroll
    for (int i = 0; i < 4; ++i) {
        int m = m0 + 4*tr + i;
        #pragma unroll
        for (int j = 0; j < 4; ++j) {
            int n = 4*tc + j;
            if (n < N) C[(long long)m * N + n] = acc[i][j] + bias[n];
        }
    }
}

// ---------------------------------------------------------------------------
// CRF: forward logsumexp scan + log_z + gold score + loss, one block per b.
// ---------------------------------------------------------------------------
__global__ __launch_bounds__(1024) void crf_kernel(
    const float* __restrict__ feats,
    const float* __restrict__ trans,
    const int*   __restrict__ tokens,
    const int*   __restrict__ tags,
    const int*   __restrict__ lengths,
    float* __restrict__ out)
{
    const int b = blockIdx.x;
    const int tid = threadIdx.x;
    __shared__ float tr_s[KTAGS*KTAGS];
    __shared__ float score_s[KTAGS];
    __shared__ float emit_s[KTAGS];
    __shared__ float red_s[16];
    __shared__ float logz_s;

    tr_s[tid] = trans[tid];
    if (tid < KTAGS) score_s[tid] = (tid == START_TAG) ? 0.0f : NEGV;
    __syncthreads();

    const int i = tid >> 5, j = tid & 31;
    for (int t = 0; t < T_STEPS; ++t) {
        if (tid < KTAGS) emit_s[tid] = feats[((long long)t*BATCH + b)*KTAGS + tid];
        __syncthreads();
        float e = score_s[j] + tr_s[i*KTAGS + j];
        float m = e;
        m = fmaxf(m, __shfl_xor(m, 1));  m = fmaxf(m, __shfl_xor(m, 2));
        m = fmaxf(m, __shfl_xor(m, 4));  m = fmaxf(m, __shfl_xor(m, 8));
        m = fmaxf(m, __shfl_xor(m, 16));
        float p = __expf(e - m);
        p += __shfl_xor(p, 1); p += __shfl_xor(p, 2); p += __shfl_xor(p, 4);
        p += __shfl_xor(p, 8); p += __shfl_xor(p, 16);
        float nv = m + __logf(p) + emit_s[i];
        int msk = tokens[(long long)t*BATCH + b] > 0;
        __syncthreads();
        if (j == 0) score_s[i] = msk ? nv : score_s[i];
        __syncthreads();
    }

    if (tid < KTAGS) {
        float v = score_s[tid] + tr_s[END_TAG*KTAGS + tid];
        float m = v;
        m = fmaxf(m, __shfl_xor(m, 1));  m = fmaxf(m, __shfl_xor(m, 2));
        m = fmaxf(m, __shfl_xor(m, 4));  m = fmaxf(m, __shfl_xor(m, 8));
        m = fmaxf(m, __shfl_xor(m, 16));
        float p = __expf(v - m);
        p += __shfl_xor(p, 1); p += __shfl_xor(p, 2); p += __shfl_xor(p, 4);
        p += __shfl_xor(p, 8); p += __shfl_xor(p, 16);
        if (tid == 0) logz_s = m + __logf(p);
    }
    __syncthreads();

    float val = 0.0f;
    if (tid < T_STEPS) {
        int t = tid;
        int cur  = tags[(long long)t*BATCH + b];
        int prev = (t == 0) ? START_TAG : tags[(long long)(t-1)*BATCH + b];
        int msk  = tokens[(long long)t*BATCH + b] > 0;
        if (msk) val = tr_s[cur*KTAGS + prev]
                     + feats[((long long)t*BATCH + b)*KTAGS + cur];
    }
    val += __shfl_xor(val, 1);  val += __shfl_xor(val, 2);
    val += __shfl_xor(val, 4);  val += __shfl_xor(val, 8);
    val += __shfl_xor(val, 16); val += __shfl_xor(val, 32);
    int wave = tid >> 6, lane = tid & 63;
    if (lane == 0) red_s[wave] = val;
    __syncthreads();
    if (tid == 0) {
        float g = 0.0f;
        #pragma unroll
        for (int w = 0; w < 16; ++w) g += red_s[w];
        g += tr_s[END_TAG*KTAGS + tags[(long long)(T_STEPS-1)*BATCH + b]];
        atomicAdd(out, (logz_s - g) / (float)lengths[b]);
    }
}

// ---------------------------------------------------------------------------
extern "C" void kernel_launch(void* const* d_in, const int* in_sizes, int n_in,
                              void* d_out, int out_size, void* d_ws, size_t ws_size,
                              hipStream_t stream) {
    const int*   tokens  = (const int*)  d_in[0];
    const int*   tags    = (const int*)  d_in[1];
    const int*   lengths = (const int*)  d_in[2];
    const float* embed   = (const float*)d_in[3];
    const float* wih0    = (const float*)d_in[4];
    const float* whh0    = (const float*)d_in[5];
    const float* b0      = (const float*)d_in[6];
    const float* wih1    = (const float*)d_in[7];
    const float* whh1    = (const float*)d_in[8];
    const float* b1      = (const float*)d_in[9];
    const float* lin_w   = (const float*)d_in[10];
    const float* lin_b   = (const float*)d_in[11];
    const float* trans   = (const float*)d_in[12];

    // Workspace layout (total ~123.2 MiB, unchanged)
    char* ws = (char*)d_ws;
    unsigned short* hs0   = (unsigned short*)(ws);                   // 33,554,432
    unsigned short* hs1   = (unsigned short*)(ws +  33554432ULL);    // 33,554,432
    unsigned short* embB  = (unsigned short*)(ws +  67108864ULL);    // 32,768,000
    unsigned short* wp0   = (unsigned short*)(ws +  99876864ULL);    //  8,388,608
    unsigned short* wp1   = (unsigned short*)(ws + 108265472ULL);    // 12,582,912
    float*          feats = (float*)        (ws + 120848384ULL);     //  2,097,152
    unsigned long long* hbuf = (unsigned long long*)(ws + 122945536ULL); // 262,144
    unsigned int*   flags = (unsigned int*) (ws + 123207680ULL);     //  4,096

    float* out = (float*)d_out;

    init_zero<<<dim3(5), 256, 0, stream>>>(flags, out);
    convert_embed<<<dim3(16000), 256, 0, stream>>>(embed, embB);
    pack_w<<<dim3(2048), 256, 0, stream>>>(wih0, whh0, 512,  wp0);
    pack_w<<<dim3(3072), 256, 0, stream>>>(wih1, whh1, 1024, wp1);

    lstm_mfma<<<dim3(NBLK), 256, 0, stream>>>(
        tokens, embB, wp0, wp1, b0, b1, hs0, hs1, hbuf,
        (unsigned short*)flags);

    gemm_feats<<<dim3(1, 256, 1), 256, 0, stream>>>(
        hs1, lin_w, lin_b, feats, T_STEPS*BATCH, KTAGS, 2*HID);

    crf_kernel<<<dim3(BATCH), 1024, 0, stream>>>(feats, trans, tokens, tags,
                                                 lengths, out);
}

// Round 2
// 3770.866 us; speedup vs baseline: 1.4852x; 1.4852x over previous
//
#include <hip/hip_runtime.h>
#include <math.h>

// Problem constants (V,E,H,K,T,B) = (32000, 512, 512, 32, 256, 64)
#define T_STEPS 256
#define BATCH   64
#define HID     512
#define KTAGS   32
#define NEGV    -100000.0f
#define START_TAG 30
#define END_TAG   31

#define NBLK      256
#define SPIN_LIM  (1 << 26)
#define LAYER_DONE 300u

typedef __attribute__((ext_vector_type(8))) short short8;
typedef __attribute__((ext_vector_type(4))) float f32x4;

union V16 { uint4 u; short8 s; };
union HQ  { unsigned long long q[2]; short8 s; };

static __device__ __forceinline__ unsigned short f2b(float f) {
    unsigned u = __float_as_uint(f);
    return (unsigned short)((u + 0x7fffu + ((u >> 16) & 1u)) >> 16);
}
static __device__ __forceinline__ float b2f(unsigned short us) {
    return __uint_as_float(((unsigned)us) << 16);
}

// ---------------------------------------------------------------------------
// Init: zero padded flag region (agent-scope — step kernel reads flags via
// agent atomics which bypass local L2) + d_out.
// Padded flags: 4 regions (l,d) x 128 blocks x 1 u32 per 128B line = 64 KiB.
// ---------------------------------------------------------------------------
__global__ __launch_bounds__(256) void init_zero(unsigned int* __restrict__ flags,
                                                 float* __restrict__ out)
{
    int i = blockIdx.x * 256 + threadIdx.x;
    if (i < 16384)
        __hip_atomic_store(flags + i, 0u, __ATOMIC_RELAXED, __HIP_MEMORY_SCOPE_AGENT);
    if (i == 0)
        __hip_atomic_store(out, 0.0f, __ATOMIC_RELAXED, __HIP_MEMORY_SCOPE_AGENT);
}

// ---------------------------------------------------------------------------
// embed fp32 -> bf16 (one-time, 16.4M elements)
// ---------------------------------------------------------------------------
__global__ __launch_bounds__(256) void convert_embed(const float* __restrict__ src,
                                                     unsigned short* __restrict__ dst)
{
    long long i = ((long long)blockIdx.x * 256 + threadIdx.x) * 4;
    if (i >= (long long)32000 * 512) return;
    float4 v = *(const float4*)(src + i);
    ushort4 o;
    o.x = f2b(v.x); o.y = f2b(v.y); o.z = f2b(v.z); o.w = f2b(v.w);
    *(ushort4*)(dst + i) = o;
}

// ---------------------------------------------------------------------------
// Pack Wih|Whh (fp32) into bf16 MFMA B-fragment stream (unchanged).
// ---------------------------------------------------------------------------
__global__ __launch_bounds__(256) void pack_w(const float* __restrict__ wih,
                                              const float* __restrict__ whh,
                                              int xK,
                                              unsigned short* __restrict__ wpack)
{
    const int xKt = xK >> 5, KT = xKt + 16;
    long long t = (long long)blockIdx.x * 256 + threadIdx.x;
    if (t >= (long long)2 * 128 * KT * 64) return;
    int lane = (int)(t & 63);
    long long rest = t >> 6;
    int kt = (int)(rest % KT); rest /= KT;
    int nt = (int)(rest % 128);
    int d  = (int)(rest / 128);
    int c = lane & 15, q = lane >> 4;
    int r = (c >> 2) * 512 + nt * 4 + (c & 3);
    const float* src;
    if (kt < xKt) src = wih + ((long long)d * 2048 * xK + (long long)r * xK + kt * 32 + q * 8);
    else          src = whh + ((long long)d * 2048 * 512 + (long long)r * 512 + (kt - xKt) * 32 + q * 8);
    float4 v0 = *(const float4*)src;
    float4 v1 = *(const float4*)(src + 4);
    unsigned short o[8] = { f2b(v0.x), f2b(v0.y), f2b(v0.z), f2b(v0.w),
                            f2b(v1.x), f2b(v1.y), f2b(v1.z), f2b(v1.w) };
    *(uint4*)(wpack + t * 8) = *(const uint4*)o;
}

// ---------------------------------------------------------------------------
// Persistent BiLSTM, MFMA edition — baseline (4500us) compute structure,
// with the cross-block exchange re-laid-out to kill IF line serialization:
//  - hbuf is BLOCK-MAJOR: [par][d][nt][b] u64. Producer block nt stores its
//    64 h-quads as one coalesced 512B burst into 4 exclusively-owned lines
//    (old layout: every 128B line had 16 writer blocks). Consumer 16-lane
//    groups read CONSECUTIVE u64s -> 8 line requests/instr instead of 64.
//  - flags padded to 1 u32 per 128B line (no shared-line stores, no RMW
//    fan-in chain). Consumer: wave-0 parallel poll, 64 lanes x 2 flags,
//    __all ballot.
// Ordering discipline unchanged: h stores drained with s_waitcnt vmcnt(0),
// __syncthreads, then tid0 stores the per-block flag (relaxed agent).
// ---------------------------------------------------------------------------
__global__ __launch_bounds__(256) void lstm_mfma(
    const int* __restrict__ tokens,
    const unsigned short* __restrict__ embB,   // [32000][512] bf16
    const unsigned short* __restrict__ wp0,    // packed L0 weights
    const unsigned short* __restrict__ wp1,    // packed L1 weights
    const float* __restrict__ bb0, const float* __restrict__ bb1,
    unsigned short* __restrict__ hs0,          // [T][B][1024] bf16
    unsigned short* __restrict__ hs1,
    unsigned long long* __restrict__ hbuf64,   // [2 par][2 d][128 nt][64 b]
    unsigned int* __restrict__ flags)          // 4 x 128 x 32 u32 (128B pad)
{
    __shared__ int   tok_s[64];
    __shared__ float Gred[4][64][17];
    __shared__ float hsh[64][4];

    const int bid = blockIdx.x;
    const int d   = bid >> 7;
    const int nt  = bid & 127;
    const int tid = threadIdx.x;
    const int w    = tid >> 6;
    const int lane = tid & 63;
    const int lm = lane & 15, q = lane >> 4;
    const int gm = tid >> 2, gj = tid & 3;     // gate-phase cell (batch, hcol-off)

    bool dead = false;
    float creg = 0.0f;

    for (int l = 0; l < 2; ++l) {
        const int xK  = l ? 1024 : 512;
        const int xKt = xK >> 5;
        const int KT  = xKt + 16;
        const int nX  = xKt >> 2;              // X-phase kts per wave
        const unsigned short* wp = (l ? wp1 : wp0) + ((long long)(d * 128 + nt)) * KT * 512;
        const float* bia = (l ? bb1 : bb0) + (long long)d * 2048;
        unsigned short* hso = l ? hs1 : hs0;
        unsigned int* flg = flags + (l * 2 + d) * 4096;   // region: 128 x 32 u32

        float breg[4];
        #pragma unroll
        for (int g = 0; g < 4; ++g) breg[g] = bia[g * 512 + nt * 4 + gj];
        creg = 0.0f;

        for (int s = 0; s < T_STEPS; ++s) {
            const int tt = d ? (T_STEPS - 1 - s) : s;

            f32x4 acc[4];
            #pragma unroll
            for (int mt = 0; mt < 4; ++mt) acc[mt] = (f32x4)0.0f;

            if (l == 0 && tid < 64) tok_s[tid] = tokens[tt * BATCH + tid];
            __syncthreads();

            // A-row base pointers for this step (lane-dependent row lm)
            const unsigned short* xr[4];
            #pragma unroll
            for (int mt = 0; mt < 4; ++mt) {
                int m = mt * 16 + lm;
                if (l == 0) xr[mt] = embB + (long long)tok_s[m] * 512;
                else        xr[mt] = hs0 + ((long long)tt * 64 + m) * 1024;
            }

            // ---------------- X phase (no h dependency) ---------------------
            for (int i = 0; i < nX; ++i) {
                const int kt = w * nX + i;
                V16 bv; bv.u = *(const uint4*)(wp + (long long)kt * 512 + lane * 8);
                #pragma unroll
                for (int mt = 0; mt < 4; ++mt) {
                    V16 av; av.u = *(const uint4*)(xr[mt] + kt * 32 + q * 8);
                    acc[mt] = __builtin_amdgcn_mfma_f32_16x16x32_bf16(av.s, bv.s, acc[mt], 0, 0, 0);
                }
            }

            // ---------------- wait h(s-1): wave-parallel padded-flag poll ---
            if (s > 0) {
                if (tid < 64 && !dead) {
                    int n = 0;
                    for (;;) {
                        unsigned a = __hip_atomic_load(flg + tid * 32, __ATOMIC_RELAXED,
                                                       __HIP_MEMORY_SCOPE_AGENT);
                        unsigned b = __hip_atomic_load(flg + (tid + 64) * 32, __ATOMIC_RELAXED,
                                                       __HIP_MEMORY_SCOPE_AGENT);
                        if (__all(a >= (unsigned)s && b >= (unsigned)s)) break;
                        __builtin_amdgcn_s_sleep(1);
                        if (++n > SPIN_LIM) { dead = true; break; }
                    }
                }
                __syncthreads();
                const unsigned long long* hb =
                    hbuf64 + (long long)(((s - 1) & 1) * 2 + d) * 8192;
                #pragma unroll
                for (int i = 0; i < 4; ++i) {
                    const int kth = w * 4 + i;
                    V16 bv; bv.u = *(const uint4*)(wp + (long long)(xKt + kth) * 512 + lane * 8);
                    #pragma unroll
                    for (int mt = 0; mt < 4; ++mt) {
                        const int m = mt * 16 + lm;
                        const int nt0 = kth * 8 + q * 2;        // block owning cols q*8..q*8+3
                        HQ h;
                        h.q[0] = __hip_atomic_load(hb + nt0 * 64 + m,      __ATOMIC_RELAXED, __HIP_MEMORY_SCOPE_AGENT);
                        h.q[1] = __hip_atomic_load(hb + nt0 * 64 + 64 + m, __ATOMIC_RELAXED, __HIP_MEMORY_SCOPE_AGENT);
                        acc[mt] = __builtin_amdgcn_mfma_f32_16x16x32_bf16(h.s, bv.s, acc[mt], 0, 0, 0);
                    }
                }
            }

            // ---------------- K-reduce across waves + gates -----------------
            #pragma unroll
            for (int mt = 0; mt < 4; ++mt)
                #pragma unroll
                for (int r = 0; r < 4; ++r)
                    Gred[w][mt * 16 + q * 4 + r][lm] = acc[mt][r];
            __syncthreads();

            float vg[4];
            #pragma unroll
            for (int g = 0; g < 4; ++g) {
                float v = breg[g];
                #pragma unroll
                for (int ww = 0; ww < 4; ++ww) v += Gred[ww][gm][g * 4 + gj];
                vg[g] = v;
            }
            const float si = 1.0f / (1.0f + __expf(-vg[0]));
            const float sf = 1.0f / (1.0f + __expf(-vg[1]));
            const float so = 1.0f / (1.0f + __expf(-vg[3]));
            const float cn = sf * creg + si * tanhf(vg[2]);
            const float hn = so * tanhf(cn);
            creg = cn;
            hsh[gm][gj] = hn;
            __syncthreads();

            // ---------------- publish h (coalesced, exclusive lines) --------
            if (tid < 64) {
                const int b = tid;
                unsigned long long hv =
                      (unsigned long long)f2b(hsh[b][0])
                    | ((unsigned long long)f2b(hsh[b][1]) << 16)
                    | ((unsigned long long)f2b(hsh[b][2]) << 32)
                    | ((unsigned long long)f2b(hsh[b][3]) << 48);
                unsigned long long* dst =
                    hbuf64 + (long long)((s & 1) * 2 + d) * 8192 + nt * 64 + b;
                __hip_atomic_store(dst, hv, __ATOMIC_RELAXED, __HIP_MEMORY_SCOPE_AGENT);
                *(unsigned long long*)(hso + ((long long)tt * 64 + b) * 1024 + d * 512 + nt * 4) = hv;
            }
            asm volatile("s_waitcnt vmcnt(0)" ::: "memory");
            __syncthreads();
            if (tid == 0)
                __hip_atomic_store(flg + nt * 32, (unsigned)(s + 1),
                                   __ATOMIC_RELAXED, __HIP_MEMORY_SCOPE_AGENT);
        }

        // ------------- layer boundary: publish hs0 for cached L1 reads ------
        if (l == 0) {
            __threadfence();                    // wb dirty hs0 out of local L2
            __syncthreads();
            if (tid == 0)
                __hip_atomic_store(flags + d * 4096 + nt * 32, LAYER_DONE,
                                   __ATOMIC_RELAXED, __HIP_MEMORY_SCOPE_AGENT);
            if (tid < 64) {                     // wait both l=0 regions done
                int n = 0;
                for (;;) {
                    unsigned a = __hip_atomic_load(flags + tid * 32,          __ATOMIC_RELAXED, __HIP_MEMORY_SCOPE_AGENT);
                    unsigned b = __hip_atomic_load(flags + (tid + 64) * 32,   __ATOMIC_RELAXED, __HIP_MEMORY_SCOPE_AGENT);
                    unsigned c = __hip_atomic_load(flags + 4096 + tid * 32,   __ATOMIC_RELAXED, __HIP_MEMORY_SCOPE_AGENT);
                    unsigned e = __hip_atomic_load(flags + 4096 + (tid + 64) * 32, __ATOMIC_RELAXED, __HIP_MEMORY_SCOPE_AGENT);
                    if (__all(a >= LAYER_DONE && b >= LAYER_DONE &&
                              c >= LAYER_DONE && e >= LAYER_DONE)) break;
                    __builtin_amdgcn_s_sleep(1);
                    if (++n > SPIN_LIM) break;
                }
            }
            __syncthreads();
            __threadfence();                    // inv stale lines before cached reads
        }
    }
}

// ---------------------------------------------------------------------------
// feats = hs1(bf16) @ lin_w^T + lin_b   (64-row tiles, N=32)
// ---------------------------------------------------------------------------
__global__ __launch_bounds__(256) void gemm_feats(
    const unsigned short* __restrict__ A,      // [M][1024] bf16
    const float* __restrict__ W,               // [32][1024]
    const float* __restrict__ bias,
    float* __restrict__ C,
    int M, int N, int K)
{
    __shared__ __align__(16) float As[64][34];
    __shared__ __align__(16) float Ws[32][68];

    const int m0 = blockIdx.y * 64;
    const int tid = threadIdx.x;
    const int tr = tid >> 4;
    const int tc = tid & 15;

    float acc[4][4];
    #pragma unroll
    for (int i = 0; i < 4; ++i)
        #pragma unroll
        for (int j = 0; j < 4; ++j) acc[i][j] = 0.0f;

    for (int k0 = 0; k0 < K; k0 += 32) {
        {   // A tile: 64 rows x 32 k (bf16 -> f32)
            int row = tid >> 2, g8 = tid & 3;
            uint4 v = *(const uint4*)(A + ((long long)(m0 + row)) * 1024 + k0 + g8 * 8);
            const unsigned short* pv = (const unsigned short*)&v;
            #pragma unroll
            for (int e = 0; e < 8; ++e) As[row][g8 * 8 + e] = b2f(pv[e]);
        }
        {   // W tile: 32 rows x 32 k, transposed
            int row = tid >> 3, q2 = tid & 7;
            float4 v = *(const float4*)(W + (long long)row * K + k0 + 4 * q2);
            Ws[4*q2+0][row] = v.x; Ws[4*q2+1][row] = v.y;
            Ws[4*q2+2][row] = v.z; Ws[4*q2+3][row] = v.w;
        }
        __syncthreads();
        #pragma unroll 8
        for (int kk = 0; kk < 32; ++kk) {
            float a0 = As[4*tr+0][kk], a1 = As[4*tr+1][kk];
            float a2 = As[4*tr+2][kk], a3 = As[4*tr+3][kk];
            float4 wv = *(const float4*)&Ws[kk][4*tc];
            acc[0][0] += a0*wv.x; acc[0][1] += a0*wv.y; acc[0][2] += a0*wv.z; acc[0][3] += a0*wv.w;
            acc[1][0] += a1*wv.x; acc[1][1] += a1*wv.y; acc[1][2] += a1*wv.z; acc[1][3] += a1*wv.w;
            acc[2][0] += a2*wv.x; acc[2][1] += a2*wv.y; acc[2][2] += a2*wv.z; acc[2][3] += a2*wv.w;
            acc[3][0] += a3*wv.x; acc[3][1] += a3*wv.y; acc[3][2] += a3*wv.z; acc[3][3] += a3*wv.w;
        }
        __syncthreads();
    }
    #pragma unroll
    for (int i = 0; i < 4; ++i) {
        int m = m0 + 4*tr + i;
        #pragma unroll
        for (int j = 0; j < 4; ++j) {
            int n = 4*tc + j;
            if (n < N) C[(long long)m * N + n] = acc[i][j] + bias[n];
        }
    }
}

// ---------------------------------------------------------------------------
// CRF: forward logsumexp scan + log_z + gold score + loss, one block per b.
// ---------------------------------------------------------------------------
__global__ __launch_bounds__(1024) void crf_kernel(
    const float* __restrict__ feats,
    const float* __restrict__ trans,
    const int*   __restrict__ tokens,
    const int*   __restrict__ tags,
    const int*   __restrict__ lengths,
    float* __restrict__ out)
{
    const int b = blockIdx.x;
    const int tid = threadIdx.x;
    __shared__ float tr_s[KTAGS*KTAGS];
    __shared__ float score_s[KTAGS];
    __shared__ float emit_s[KTAGS];
    __shared__ float red_s[16];
    __shared__ float logz_s;

    tr_s[tid] = trans[tid];
    if (tid < KTAGS) score_s[tid] = (tid == START_TAG) ? 0.0f : NEGV;
    __syncthreads();

    const int i = tid >> 5, j = tid & 31;
    for (int t = 0; t < T_STEPS; ++t) {
        if (tid < KTAGS) emit_s[tid] = feats[((long long)t*BATCH + b)*KTAGS + tid];
        __syncthreads();
        float e = score_s[j] + tr_s[i*KTAGS + j];
        float m = e;
        m = fmaxf(m, __shfl_xor(m, 1));  m = fmaxf(m, __shfl_xor(m, 2));
        m = fmaxf(m, __shfl_xor(m, 4));  m = fmaxf(m, __shfl_xor(m, 8));
        m = fmaxf(m, __shfl_xor(m, 16));
        float p = __expf(e - m);
        p += __shfl_xor(p, 1); p += __shfl_xor(p, 2); p += __shfl_xor(p, 4);
        p += __shfl_xor(p, 8); p += __shfl_xor(p, 16);
        float nv = m + __logf(p) + emit_s[i];
        int msk = tokens[(long long)t*BATCH + b] > 0;
        __syncthreads();
        if (j == 0) score_s[i] = msk ? nv : score_s[i];
        __syncthreads();
    }

    if (tid < KTAGS) {
        float v = score_s[tid] + tr_s[END_TAG*KTAGS + tid];
        float m = v;
        m = fmaxf(m, __shfl_xor(m, 1));  m = fmaxf(m, __shfl_xor(m, 2));
        m = fmaxf(m, __shfl_xor(m, 4));  m = fmaxf(m, __shfl_xor(m, 8));
        m = fmaxf(m, __shfl_xor(m, 16));
        float p = __expf(v - m);
        p += __shfl_xor(p, 1); p += __shfl_xor(p, 2); p += __shfl_xor(p, 4);
        p += __shfl_xor(p, 8); p += __shfl_xor(p, 16);
        if (tid == 0) logz_s = m + __logf(p);
    }
    __syncthreads();

    float val = 0.0f;
    if (tid < T_STEPS) {
        int t = tid;
        int cur  = tags[(long long)t*BATCH + b];
        int prev = (t == 0) ? START_TAG : tags[(long long)(t-1)*BATCH + b];
        int msk  = tokens[(long long)t*BATCH + b] > 0;
        if (msk) val = tr_s[cur*KTAGS + prev]
                     + feats[((long long)t*BATCH + b)*KTAGS + cur];
    }
    val += __shfl_xor(val, 1);  val += __shfl_xor(val, 2);
    val += __shfl_xor(val, 4);  val += __shfl_xor(val, 8);
    val += __shfl_xor(val, 16); val += __shfl_xor(val, 32);
    int wave = tid >> 6, lane = tid & 63;
    if (lane == 0) red_s[wave] = val;
    __syncthreads();
    if (tid == 0) {
        float g = 0.0f;
        #pragma unroll
        for (int w = 0; w < 16; ++w) g += red_s[w];
        g += tr_s[END_TAG*KTAGS + tags[(long long)(T_STEPS-1)*BATCH + b]];
        atomicAdd(out, (logz_s - g) / (float)lengths[b]);
    }
}

// ---------------------------------------------------------------------------
extern "C" void kernel_launch(void* const* d_in, const int* in_sizes, int n_in,
                              void* d_out, int out_size, void* d_ws, size_t ws_size,
                              hipStream_t stream) {
    const int*   tokens  = (const int*)  d_in[0];
    const int*   tags    = (const int*)  d_in[1];
    const int*   lengths = (const int*)  d_in[2];
    const float* embed   = (const float*)d_in[3];
    const float* wih0    = (const float*)d_in[4];
    const float* whh0    = (const float*)d_in[5];
    const float* b0      = (const float*)d_in[6];
    const float* wih1    = (const float*)d_in[7];
    const float* whh1    = (const float*)d_in[8];
    const float* b1      = (const float*)d_in[9];
    const float* lin_w   = (const float*)d_in[10];
    const float* lin_b   = (const float*)d_in[11];
    const float* trans   = (const float*)d_in[12];

    // Workspace layout (total ~123.2 MiB, unchanged footprint).
    // Padded flag region (64 KiB) lives INSIDE the feats buffer: feats is
    // dead until gemm_feats runs (after lstm_mfma completes), so the LSTM
    // can use its first 64 KiB for sync flags.
    char* ws = (char*)d_ws;
    unsigned short* hs0   = (unsigned short*)(ws);                   // 33,554,432
    unsigned short* hs1   = (unsigned short*)(ws +  33554432ULL);    // 33,554,432
    unsigned short* embB  = (unsigned short*)(ws +  67108864ULL);    // 32,768,000
    unsigned short* wp0   = (unsigned short*)(ws +  99876864ULL);    //  8,388,608
    unsigned short* wp1   = (unsigned short*)(ws + 108265472ULL);    // 12,582,912
    float*          feats = (float*)        (ws + 120848384ULL);     //  2,097,152
    unsigned long long* hbuf = (unsigned long long*)(ws + 122945536ULL); // 262,144
    unsigned int*   flagsP = (unsigned int*)feats;                   // 65,536 (dead until gemm)

    float* out = (float*)d_out;

    init_zero<<<dim3(64), 256, 0, stream>>>(flagsP, out);
    convert_embed<<<dim3(16000), 256, 0, stream>>>(embed, embB);
    pack_w<<<dim3(2048), 256, 0, stream>>>(wih0, whh0, 512,  wp0);
    pack_w<<<dim3(3072), 256, 0, stream>>>(wih1, whh1, 1024, wp1);

    lstm_mfma<<<dim3(NBLK), 256, 0, stream>>>(
        tokens, embB, wp0, wp1, b0, b1, hs0, hs1, hbuf, flagsP);

    gemm_feats<<<dim3(1, 256, 1), 256, 0, stream>>>(
        hs1, lin_w, lin_b, feats, T_STEPS*BATCH, KTAGS, 2*HID);

    crf_kernel<<<dim3(BATCH), 1024, 0, stream>>>(feats, trans, tokens, tags,
                                                 lengths, out);
}

// Round 3
// 3476.350 us; speedup vs baseline: 1.6110x; 1.0847x over previous
//
#include <hip/hip_runtime.h>
#include <math.h>

// Problem constants (V,E,H,K,T,B) = (32000, 512, 512, 32, 256, 64)
#define T_STEPS 256
#define BATCH   64
#define HID     512
#define KTAGS   32
#define NEGV    -100000.0f
#define START_TAG 30
#define END_TAG   31

#define NBLK      256
#define SPIN_LIM  (1 << 26)
#define LAYER_DONE  300u
#define POISON_DONE 301u
#define POISON    0xFFFFFFFFFFFFFFFFULL

typedef __attribute__((ext_vector_type(8))) short short8;
typedef __attribute__((ext_vector_type(4))) float f32x4;

union V16 { uint4 u; short8 s; };
union HQ  { unsigned long long q[2]; short8 s; };

static __device__ __forceinline__ unsigned short f2b(float f) {
    unsigned u = __float_as_uint(f);
    return (unsigned short)((u + 0x7fffu + ((u >> 16) & 1u)) >> 16);
}
static __device__ __forceinline__ float b2f(unsigned short us) {
    return __uint_as_float(((unsigned)us) << 16);
}

// ---------------------------------------------------------------------------
// Init: poison all 16 h-exchange buffers (8 parities x 2 dirs x 64KB = 1MB),
// zero padded flag region, zero d_out. All agent-scope (step kernel reads
// these via agent atomics which bypass the local L2).
// ---------------------------------------------------------------------------
__global__ __launch_bounds__(256) void init_zero(unsigned int* __restrict__ flags,
                                                 unsigned long long* __restrict__ hbuf,
                                                 float* __restrict__ out)
{
    int i = blockIdx.x * 256 + threadIdx.x;
    if (i < 131072)
        __hip_atomic_store(hbuf + i, POISON, __ATOMIC_RELAXED, __HIP_MEMORY_SCOPE_AGENT);
    if (i < 16384)
        __hip_atomic_store(flags + i, 0u, __ATOMIC_RELAXED, __HIP_MEMORY_SCOPE_AGENT);
    if (i == 0)
        __hip_atomic_store(out, 0.0f, __ATOMIC_RELAXED, __HIP_MEMORY_SCOPE_AGENT);
}

// ---------------------------------------------------------------------------
// embed fp32 -> bf16 (one-time, 16.4M elements)
// ---------------------------------------------------------------------------
__global__ __launch_bounds__(256) void convert_embed(const float* __restrict__ src,
                                                     unsigned short* __restrict__ dst)
{
    long long i = ((long long)blockIdx.x * 256 + threadIdx.x) * 4;
    if (i >= (long long)32000 * 512) return;
    float4 v = *(const float4*)(src + i);
    ushort4 o;
    o.x = f2b(v.x); o.y = f2b(v.y); o.z = f2b(v.z); o.w = f2b(v.w);
    *(ushort4*)(dst + i) = o;
}

// ---------------------------------------------------------------------------
// Pack Wih|Whh (fp32) into bf16 MFMA B-fragment stream (unchanged).
// ---------------------------------------------------------------------------
__global__ __launch_bounds__(256) void pack_w(const float* __restrict__ wih,
                                              const float* __restrict__ whh,
                                              int xK,
                                              unsigned short* __restrict__ wpack)
{
    const int xKt = xK >> 5, KT = xKt + 16;
    long long t = (long long)blockIdx.x * 256 + threadIdx.x;
    if (t >= (long long)2 * 128 * KT * 64) return;
    int lane = (int)(t & 63);
    long long rest = t >> 6;
    int kt = (int)(rest % KT); rest /= KT;
    int nt = (int)(rest % 128);
    int d  = (int)(rest / 128);
    int c = lane & 15, q = lane >> 4;
    int r = (c >> 2) * 512 + nt * 4 + (c & 3);
    const float* src;
    if (kt < xKt) src = wih + ((long long)d * 2048 * xK + (long long)r * xK + kt * 32 + q * 8);
    else          src = whh + ((long long)d * 2048 * 512 + (long long)r * 512 + (kt - xKt) * 32 + q * 8);
    float4 v0 = *(const float4*)src;
    float4 v1 = *(const float4*)(src + 4);
    unsigned short o[8] = { f2b(v0.x), f2b(v0.y), f2b(v0.z), f2b(v0.w),
                            f2b(v1.x), f2b(v1.y), f2b(v1.z), f2b(v1.w) };
    *(uint4*)(wpack + t * 8) = *(const uint4*)o;
}

// ---------------------------------------------------------------------------
// Persistent BiLSTM, MFMA edition — round-2 structure (block-major hbuf,
// padded flags) with the per-step flag hop ELIMINATED: consumers poll the
// h data itself.
//  - hbuf: [8 par][2 d][128 nt][64 b] u64. A u64 of 4 bf16 h-values can
//    never be all-ones (h = sigmoid*tanh is finite, 0xFFFF bf16 is NaN),
//    so POISON = ~0ULL marks "not yet written". Producer's data store IS
//    the ready signal: no vmcnt drain, no flag store, no flag poll.
//  - Producer at step s publishes parity s&7 and re-poisons parity (s+2)&7
//    (its own exclusive 512B region). Same-address program order gives
//    poison-before-data; block skew <=1 within a direction makes the +2
//    look-ahead race-free (parity being poisoned was last read at s-5).
//  - Consumer: prime-burst all 32 u64s, then re-load only still-poisoned
//    words until a full clean pass. Per-lane divergent, reconverges before
//    the MFMAs.
//  - Flags (padded 1 u32/128B line) now used ONLY at the layer boundary:
//    two-phase barrier (LAYER_DONE -> all-parity poison -> vmcnt drain ->
//    POISON_DONE) so L1 starts with a clean sentinel state.
// ---------------------------------------------------------------------------
__global__ __launch_bounds__(256) void lstm_mfma(
    const int* __restrict__ tokens,
    const unsigned short* __restrict__ embB,   // [32000][512] bf16
    const unsigned short* __restrict__ wp0,    // packed L0 weights
    const unsigned short* __restrict__ wp1,    // packed L1 weights
    const float* __restrict__ bb0, const float* __restrict__ bb1,
    unsigned short* __restrict__ hs0,          // [T][B][1024] bf16
    unsigned short* __restrict__ hs1,
    unsigned long long* __restrict__ hbuf64,   // [8 par][2 d][128 nt][64 b]
    unsigned int* __restrict__ flags)          // 2 x 128 x 32 u32 (128B pad)
{
    __shared__ int   tok_s[64];
    __shared__ float Gred[4][64][17];
    __shared__ float hsh[64][4];

    const int bid = blockIdx.x;
    const int d   = bid >> 7;
    const int nt  = bid & 127;
    const int tid = threadIdx.x;
    const int w    = tid >> 6;
    const int lane = tid & 63;
    const int lm = lane & 15, q = lane >> 4;
    const int gm = tid >> 2, gj = tid & 3;     // gate-phase cell (batch, hcol-off)

    float creg = 0.0f;

    for (int l = 0; l < 2; ++l) {
        const int xK  = l ? 1024 : 512;
        const int xKt = xK >> 5;
        const int KT  = xKt + 16;
        const int nX  = xKt >> 2;              // X-phase kts per wave
        const unsigned short* wp = (l ? wp1 : wp0) + ((long long)(d * 128 + nt)) * KT * 512;
        const float* bia = (l ? bb1 : bb0) + (long long)d * 2048;
        unsigned short* hso = l ? hs1 : hs0;

        float breg[4];
        #pragma unroll
        for (int g = 0; g < 4; ++g) breg[g] = bia[g * 512 + nt * 4 + gj];
        creg = 0.0f;

        for (int s = 0; s < T_STEPS; ++s) {
            const int tt = d ? (T_STEPS - 1 - s) : s;

            f32x4 acc[4];
            #pragma unroll
            for (int mt = 0; mt < 4; ++mt) acc[mt] = (f32x4)0.0f;

            if (l == 0 && tid < 64) tok_s[tid] = tokens[tt * BATCH + tid];
            __syncthreads();

            // A-row base pointers for this step (lane-dependent row lm)
            const unsigned short* xr[4];
            #pragma unroll
            for (int mt = 0; mt < 4; ++mt) {
                int m = mt * 16 + lm;
                if (l == 0) xr[mt] = embB + (long long)tok_s[m] * 512;
                else        xr[mt] = hs0 + ((long long)tt * 64 + m) * 1024;
            }

            // ---------------- X phase (no h dependency) ---------------------
            for (int i = 0; i < nX; ++i) {
                const int kt = w * nX + i;
                V16 bv; bv.u = *(const uint4*)(wp + (long long)kt * 512 + lane * 8);
                #pragma unroll
                for (int mt = 0; mt < 4; ++mt) {
                    V16 av; av.u = *(const uint4*)(xr[mt] + kt * 32 + q * 8);
                    acc[mt] = __builtin_amdgcn_mfma_f32_16x16x32_bf16(av.s, bv.s, acc[mt], 0, 0, 0);
                }
            }

            // ---------------- recurrent phase: poll the data itself ---------
            if (s > 0) {
                const unsigned long long* hb =
                    hbuf64 + (long long)(((s - 1) & 7) * 2 + d) * 8192;

                HQ hq[4][4];
                #pragma unroll
                for (int i = 0; i < 4; ++i) {              // prime burst
                    const int kth = w * 4 + i;
                    #pragma unroll
                    for (int mt = 0; mt < 4; ++mt) {
                        const int m = mt * 16 + lm;
                        const int base = (kth * 8 + q * 2) * 64 + m;
                        hq[i][mt].q[0] = __hip_atomic_load(hb + base,      __ATOMIC_RELAXED, __HIP_MEMORY_SCOPE_AGENT);
                        hq[i][mt].q[1] = __hip_atomic_load(hb + base + 64, __ATOMIC_RELAXED, __HIP_MEMORY_SCOPE_AGENT);
                    }
                }
                int n = 0;
                for (;;) {                                 // validate passes
                    int bad = 0;
                    #pragma unroll
                    for (int i = 0; i < 4; ++i) {
                        const int kth = w * 4 + i;
                        #pragma unroll
                        for (int mt = 0; mt < 4; ++mt) {
                            const int m = mt * 16 + lm;
                            const int base = (kth * 8 + q * 2) * 64 + m;
                            if (hq[i][mt].q[0] == POISON) {
                                hq[i][mt].q[0] = __hip_atomic_load(hb + base,      __ATOMIC_RELAXED, __HIP_MEMORY_SCOPE_AGENT);
                                bad = 1;
                            }
                            if (hq[i][mt].q[1] == POISON) {
                                hq[i][mt].q[1] = __hip_atomic_load(hb + base + 64, __ATOMIC_RELAXED, __HIP_MEMORY_SCOPE_AGENT);
                                bad = 1;
                            }
                        }
                    }
                    if (!bad) break;
                    __builtin_amdgcn_s_sleep(1);
                    if (++n > SPIN_LIM) break;
                }

                #pragma unroll
                for (int i = 0; i < 4; ++i) {
                    const int kth = w * 4 + i;
                    V16 bv; bv.u = *(const uint4*)(wp + (long long)(xKt + kth) * 512 + lane * 8);
                    #pragma unroll
                    for (int mt = 0; mt < 4; ++mt)
                        acc[mt] = __builtin_amdgcn_mfma_f32_16x16x32_bf16(hq[i][mt].s, bv.s, acc[mt], 0, 0, 0);
                }
            }

            // ---------------- K-reduce across waves + gates -----------------
            #pragma unroll
            for (int mt = 0; mt < 4; ++mt)
                #pragma unroll
                for (int r = 0; r < 4; ++r)
                    Gred[w][mt * 16 + q * 4 + r][lm] = acc[mt][r];
            __syncthreads();

            float vg[4];
            #pragma unroll
            for (int g = 0; g < 4; ++g) {
                float v = breg[g];
                #pragma unroll
                for (int ww = 0; ww < 4; ++ww) v += Gred[ww][gm][g * 4 + gj];
                vg[g] = v;
            }
            const float si = 1.0f / (1.0f + __expf(-vg[0]));
            const float sf = 1.0f / (1.0f + __expf(-vg[1]));
            const float so = 1.0f / (1.0f + __expf(-vg[3]));
            const float cn = sf * creg + si * tanhf(vg[2]);
            const float hn = so * tanhf(cn);
            creg = cn;
            hsh[gm][gj] = hn;
            __syncthreads();

            // ------- publish h (data store IS the signal) + poison ahead ----
            if (tid < 64) {
                const int b = tid;
                unsigned long long hv =
                      (unsigned long long)f2b(hsh[b][0])
                    | ((unsigned long long)f2b(hsh[b][1]) << 16)
                    | ((unsigned long long)f2b(hsh[b][2]) << 32)
                    | ((unsigned long long)f2b(hsh[b][3]) << 48);
                unsigned long long* dst =
                    hbuf64 + (long long)((s & 7) * 2 + d) * 8192 + nt * 64 + b;
                __hip_atomic_store(dst, hv, __ATOMIC_RELAXED, __HIP_MEMORY_SCOPE_AGENT);
                *(unsigned long long*)(hso + ((long long)tt * 64 + b) * 1024 + d * 512 + nt * 4) = hv;
                unsigned long long* pdst =
                    hbuf64 + (long long)(((s + 2) & 7) * 2 + d) * 8192 + nt * 64 + b;
                __hip_atomic_store(pdst, POISON, __ATOMIC_RELAXED, __HIP_MEMORY_SCOPE_AGENT);
            }
            // no per-step drain / flag / barrier: consumers self-validate
        }

        // ------------- layer boundary: two-phase barrier --------------------
        if (l == 0) {
            __threadfence();                    // wb dirty hs0 out of local L2
            __syncthreads();
            if (tid == 0)
                __hip_atomic_store(flags + d * 4096 + nt * 32, LAYER_DONE,
                                   __ATOMIC_RELAXED, __HIP_MEMORY_SCOPE_AGENT);
            if (tid < 64) {                     // phase 1: all blocks done L0
                int n = 0;
                for (;;) {
                    unsigned a = __hip_atomic_load(flags + tid * 32,               __ATOMIC_RELAXED, __HIP_MEMORY_SCOPE_AGENT);
                    unsigned b = __hip_atomic_load(flags + (tid + 64) * 32,        __ATOMIC_RELAXED, __HIP_MEMORY_SCOPE_AGENT);
                    unsigned c = __hip_atomic_load(flags + 4096 + tid * 32,        __ATOMIC_RELAXED, __HIP_MEMORY_SCOPE_AGENT);
                    unsigned e = __hip_atomic_load(flags + 4096 + (tid + 64) * 32, __ATOMIC_RELAXED, __HIP_MEMORY_SCOPE_AGENT);
                    if (__all(a >= LAYER_DONE && b >= LAYER_DONE &&
                              c >= LAYER_DONE && e >= LAYER_DONE)) break;
                    __builtin_amdgcn_s_sleep(1);
                    if (++n > SPIN_LIM) break;
                }
            }
            __syncthreads();
            if (tid < 64) {                     // re-poison all parities (own region)
                #pragma unroll
                for (int p = 0; p < 8; ++p) {
                    unsigned long long* pd =
                        hbuf64 + (long long)(p * 2 + d) * 8192 + nt * 64 + tid;
                    __hip_atomic_store(pd, POISON, __ATOMIC_RELAXED, __HIP_MEMORY_SCOPE_AGENT);
                }
            }
            asm volatile("s_waitcnt vmcnt(0)" ::: "memory");
            __syncthreads();
            if (tid == 0)
                __hip_atomic_store(flags + d * 4096 + nt * 32, POISON_DONE,
                                   __ATOMIC_RELAXED, __HIP_MEMORY_SCOPE_AGENT);
            if (tid < 64) {                     // phase 2: all poisons visible
                int n = 0;
                for (;;) {
                    unsigned a = __hip_atomic_load(flags + tid * 32,               __ATOMIC_RELAXED, __HIP_MEMORY_SCOPE_AGENT);
                    unsigned b = __hip_atomic_load(flags + (tid + 64) * 32,        __ATOMIC_RELAXED, __HIP_MEMORY_SCOPE_AGENT);
                    unsigned c = __hip_atomic_load(flags + 4096 + tid * 32,        __ATOMIC_RELAXED, __HIP_MEMORY_SCOPE_AGENT);
                    unsigned e = __hip_atomic_load(flags + 4096 + (tid + 64) * 32, __ATOMIC_RELAXED, __HIP_MEMORY_SCOPE_AGENT);
                    if (__all(a >= POISON_DONE && b >= POISON_DONE &&
                              c >= POISON_DONE && e >= POISON_DONE)) break;
                    __builtin_amdgcn_s_sleep(1);
                    if (++n > SPIN_LIM) break;
                }
            }
            __syncthreads();
            __threadfence();                    // inv stale lines before cached reads
        }
    }
}

// ---------------------------------------------------------------------------
// feats = hs1(bf16) @ lin_w^T + lin_b   (64-row tiles, N=32)
// ---------------------------------------------------------------------------
__global__ __launch_bounds__(256) void gemm_feats(
    const unsigned short* __restrict__ A,      // [M][1024] bf16
    const float* __restrict__ W,               // [32][1024]
    const float* __restrict__ bias,
    float* __restrict__ C,
    int M, int N, int K)
{
    __shared__ __align__(16) float As[64][34];
    __shared__ __align__(16) float Ws[32][68];

    const int m0 = blockIdx.y * 64;
    const int tid = threadIdx.x;
    const int tr = tid >> 4;
    const int tc = tid & 15;

    float acc[4][4];
    #pragma unroll
    for (int i = 0; i < 4; ++i)
        #pragma unroll
        for (int j = 0; j < 4; ++j) acc[i][j] = 0.0f;

    for (int k0 = 0; k0 < K; k0 += 32) {
        {   // A tile: 64 rows x 32 k (bf16 -> f32)
            int row = tid >> 2, g8 = tid & 3;
            uint4 v = *(const uint4*)(A + ((long long)(m0 + row)) * 1024 + k0 + g8 * 8);
            const unsigned short* pv = (const unsigned short*)&v;
            #pragma unroll
            for (int e = 0; e < 8; ++e) As[row][g8 * 8 + e] = b2f(pv[e]);
        }
        {   // W tile: 32 rows x 32 k, transposed
            int row = tid >> 3, q2 = tid & 7;
            float4 v = *(const float4*)(W + (long long)row * K + k0 + 4 * q2);
            Ws[4*q2+0][row] = v.x; Ws[4*q2+1][row] = v.y;
            Ws[4*q2+2][row] = v.z; Ws[4*q2+3][row] = v.w;
        }
        __syncthreads();
        #pragma unroll 8
        for (int kk = 0; kk < 32; ++kk) {
            float a0 = As[4*tr+0][kk], a1 = As[4*tr+1][kk];
            float a2 = As[4*tr+2][kk], a3 = As[4*tr+3][kk];
            float4 wv = *(const float4*)&Ws[kk][4*tc];
            acc[0][0] += a0*wv.x; acc[0][1] += a0*wv.y; acc[0][2] += a0*wv.z; acc[0][3] += a0*wv.w;
            acc[1][0] += a1*wv.x; acc[1][1] += a1*wv.y; acc[1][2] += a1*wv.z; acc[1][3] += a1*wv.w;
            acc[2][0] += a2*wv.x; acc[2][1] += a2*wv.y; acc[2][2] += a2*wv.z; acc[2][3] += a2*wv.w;
            acc[3][0] += a3*wv.x; acc[3][1] += a3*wv.y; acc[3][2] += a3*wv.z; acc[3][3] += a3*wv.w;
        }
        __syncthreads();
    }
    #pragma unroll
    for (int i = 0; i < 4; ++i) {
        int m = m0 + 4*tr + i;
        #pragma unroll
        for (int j = 0; j < 4; ++j) {
            int n = 4*tc + j;
            if (n < N) C[(long long)m * N + n] = acc[i][j] + bias[n];
        }
    }
}

// ---------------------------------------------------------------------------
// CRF: forward logsumexp scan + log_z + gold score + loss, one block per b.
// ---------------------------------------------------------------------------
__global__ __launch_bounds__(1024) void crf_kernel(
    const float* __restrict__ feats,
    const float* __restrict__ trans,
    const int*   __restrict__ tokens,
    const int*   __restrict__ tags,
    const int*   __restrict__ lengths,
    float* __restrict__ out)
{
    const int b = blockIdx.x;
    const int tid = threadIdx.x;
    __shared__ float tr_s[KTAGS*KTAGS];
    __shared__ float score_s[KTAGS];
    __shared__ float emit_s[KTAGS];
    __shared__ float red_s[16];
    __shared__ float logz_s;

    tr_s[tid] = trans[tid];
    if (tid < KTAGS) score_s[tid] = (tid == START_TAG) ? 0.0f : NEGV;
    __syncthreads();

    const int i = tid >> 5, j = tid & 31;
    for (int t = 0; t < T_STEPS; ++t) {
        if (tid < KTAGS) emit_s[tid] = feats[((long long)t*BATCH + b)*KTAGS + tid];
        __syncthreads();
        float e = score_s[j] + tr_s[i*KTAGS + j];
        float m = e;
        m = fmaxf(m, __shfl_xor(m, 1));  m = fmaxf(m, __shfl_xor(m, 2));
        m = fmaxf(m, __shfl_xor(m, 4));  m = fmaxf(m, __shfl_xor(m, 8));
        m = fmaxf(m, __shfl_xor(m, 16));
        float p = __expf(e - m);
        p += __shfl_xor(p, 1); p += __shfl_xor(p, 2); p += __shfl_xor(p, 4);
        p += __shfl_xor(p, 8); p += __shfl_xor(p, 16);
        float nv = m + __logf(p) + emit_s[i];
        int msk = tokens[(long long)t*BATCH + b] > 0;
        __syncthreads();
        if (j == 0) score_s[i] = msk ? nv : score_s[i];
        __syncthreads();
    }

    if (tid < KTAGS) {
        float v = score_s[tid] + tr_s[END_TAG*KTAGS + tid];
        float m = v;
        m = fmaxf(m, __shfl_xor(m, 1));  m = fmaxf(m, __shfl_xor(m, 2));
        m = fmaxf(m, __shfl_xor(m, 4));  m = fmaxf(m, __shfl_xor(m, 8));
        m = fmaxf(m, __shfl_xor(m, 16));
        float p = __expf(v - m);
        p += __shfl_xor(p, 1); p += __shfl_xor(p, 2); p += __shfl_xor(p, 4);
        p += __shfl_xor(p, 8); p += __shfl_xor(p, 16);
        if (tid == 0) logz_s = m + __logf(p);
    }
    __syncthreads();

    float val = 0.0f;
    if (tid < T_STEPS) {
        int t = tid;
        int cur  = tags[(long long)t*BATCH + b];
        int prev = (t == 0) ? START_TAG : tags[(long long)(t-1)*BATCH + b];
        int msk  = tokens[(long long)t*BATCH + b] > 0;
        if (msk) val = tr_s[cur*KTAGS + prev]
                     + feats[((long long)t*BATCH + b)*KTAGS + cur];
    }
    val += __shfl_xor(val, 1);  val += __shfl_xor(val, 2);
    val += __shfl_xor(val, 4);  val += __shfl_xor(val, 8);
    val += __shfl_xor(val, 16); val += __shfl_xor(val, 32);
    int wave = tid >> 6, lane = tid & 63;
    if (lane == 0) red_s[wave] = val;
    __syncthreads();
    if (tid == 0) {
        float g = 0.0f;
        #pragma unroll
        for (int w = 0; w < 16; ++w) g += red_s[w];
        g += tr_s[END_TAG*KTAGS + tags[(long long)(T_STEPS-1)*BATCH + b]];
        atomicAdd(out, (logz_s - g) / (float)lengths[b]);
    }
}

// ---------------------------------------------------------------------------
extern "C" void kernel_launch(void* const* d_in, const int* in_sizes, int n_in,
                              void* d_out, int out_size, void* d_ws, size_t ws_size,
                              hipStream_t stream) {
    const int*   tokens  = (const int*)  d_in[0];
    const int*   tags    = (const int*)  d_in[1];
    const int*   lengths = (const int*)  d_in[2];
    const float* embed   = (const float*)d_in[3];
    const float* wih0    = (const float*)d_in[4];
    const float* whh0    = (const float*)d_in[5];
    const float* b0      = (const float*)d_in[6];
    const float* wih1    = (const float*)d_in[7];
    const float* whh1    = (const float*)d_in[8];
    const float* b1      = (const float*)d_in[9];
    const float* lin_w   = (const float*)d_in[10];
    const float* lin_b   = (const float*)d_in[11];
    const float* trans   = (const float*)d_in[12];

    // Workspace layout (total ~123.2 MiB footprint, unchanged).
    // Flags (64 KiB) and the 8-parity h-exchange buffers (1 MiB) live INSIDE
    // the feats buffer (2 MiB): feats is dead until gemm_feats runs (after
    // lstm_mfma completes), and gemm overwrites the whole 2 MiB.
    char* ws = (char*)d_ws;
    unsigned short* hs0   = (unsigned short*)(ws);                   // 33,554,432
    unsigned short* hs1   = (unsigned short*)(ws +  33554432ULL);    // 33,554,432
    unsigned short* embB  = (unsigned short*)(ws +  67108864ULL);    // 32,768,000
    unsigned short* wp0   = (unsigned short*)(ws +  99876864ULL);    //  8,388,608
    unsigned short* wp1   = (unsigned short*)(ws + 108265472ULL);    // 12,582,912
    float*          feats = (float*)        (ws + 120848384ULL);     //  2,097,152
    unsigned int*   flagsP = (unsigned int*)feats;                   // 65,536
    unsigned long long* hbufP = (unsigned long long*)((char*)feats + 65536); // 1,048,576

    float* out = (float*)d_out;

    init_zero<<<dim3(512), 256, 0, stream>>>(flagsP, hbufP, out);
    convert_embed<<<dim3(16000), 256, 0, stream>>>(embed, embB);
    pack_w<<<dim3(2048), 256, 0, stream>>>(wih0, whh0, 512,  wp0);
    pack_w<<<dim3(3072), 256, 0, stream>>>(wih1, whh1, 1024, wp1);

    lstm_mfma<<<dim3(NBLK), 256, 0, stream>>>(
        tokens, embB, wp0, wp1, b0, b1, hs0, hs1, hbufP, flagsP);

    gemm_feats<<<dim3(1, 256, 1), 256, 0, stream>>>(
        hs1, lin_w, lin_b, feats, T_STEPS*BATCH, KTAGS, 2*HID);

    crf_kernel<<<dim3(BATCH), 1024, 0, stream>>>(feats, trans, tokens, tags,
                                                 lengths, out);
}

// Round 4
// 2859.003 us; speedup vs baseline: 1.9588x; 1.2159x over previous
//
#include <hip/hip_runtime.h>
#include <math.h>

// Problem constants (V,E,H,K,T,B) = (32000, 512, 512, 32, 256, 64)
#define T_STEPS 256
#define BATCH   64
#define HID     512
#define KTAGS   32
#define NEGV    -100000.0f
#define START_TAG 30
#define END_TAG   31

#define NBLK      256
#define SPIN_LIM  (1 << 26)
#define LAYER_DONE  300u
#define POISON_DONE 301u
#define POISON    0xFFFFFFFFFFFFFFFFULL

typedef __attribute__((ext_vector_type(8))) short short8;
typedef __attribute__((ext_vector_type(4))) float f32x4;

union V16 { uint4 u; short8 s; };
union HQ  { unsigned long long q[2]; short8 s; };

static __device__ __forceinline__ unsigned short f2b(float f) {
    unsigned u = __float_as_uint(f);
    return (unsigned short)((u + 0x7fffu + ((u >> 16) & 1u)) >> 16);
}
static __device__ __forceinline__ float b2f(unsigned short us) {
    return __uint_as_float(((unsigned)us) << 16);
}

// ---------------------------------------------------------------------------
// Init: poison h-exchange buffers (8 par x 2 d x 2 bg x 64 nt x 64 u64 = 1MB),
// zero padded flag region, zero d_out. Agent-scope stores.
// ---------------------------------------------------------------------------
__global__ __launch_bounds__(256) void init_zero(unsigned int* __restrict__ flags,
                                                 unsigned long long* __restrict__ hbuf,
                                                 float* __restrict__ out)
{
    int i = blockIdx.x * 256 + threadIdx.x;
    if (i < 131072)
        __hip_atomic_store(hbuf + i, POISON, __ATOMIC_RELAXED, __HIP_MEMORY_SCOPE_AGENT);
    if (i < 16384)
        __hip_atomic_store(flags + i, 0u, __ATOMIC_RELAXED, __HIP_MEMORY_SCOPE_AGENT);
    if (i == 0)
        __hip_atomic_store(out, 0.0f, __ATOMIC_RELAXED, __HIP_MEMORY_SCOPE_AGENT);
}

// ---------------------------------------------------------------------------
// embed fp32 -> bf16 (one-time, 16.4M elements)
// ---------------------------------------------------------------------------
__global__ __launch_bounds__(256) void convert_embed(const float* __restrict__ src,
                                                     unsigned short* __restrict__ dst)
{
    long long i = ((long long)blockIdx.x * 256 + threadIdx.x) * 4;
    if (i >= (long long)32000 * 512) return;
    float4 v = *(const float4*)(src + i);
    ushort4 o;
    o.x = f2b(v.x); o.y = f2b(v.y); o.z = f2b(v.z); o.w = f2b(v.w);
    *(ushort4*)(dst + i) = o;
}

// ---------------------------------------------------------------------------
// Pack Wih|Whh (fp32) into bf16 MFMA B-fragment stream for the new
// 64-col-block partition. Stream: [d][nt(64)][kt(KT)][nf(2)][lane(64)][j(8)].
// Block (d,nt) owns h-cols nt*8..nt*8+7 => 32 gate cols; frag nf covers
// block-cols bc = nf*16 + (lane&15), bc -> gate g = bc>>3, cc = bc&7,
// weight row r = g*512 + nt*8 + cc; k = kt*32 + (lane>>4)*8 + j.
// kt<xKt -> Wih, else Whh. Thread t == flat 16B granule => coalesced stores.
// ---------------------------------------------------------------------------
__global__ __launch_bounds__(256) void pack_w(const float* __restrict__ wih,
                                              const float* __restrict__ whh,
                                              int xK,
                                              unsigned short* __restrict__ wpack)
{
    const int xKt = xK >> 5, KT = xKt + 16;
    long long t = (long long)blockIdx.x * 256 + threadIdx.x;
    if (t >= (long long)2 * 64 * KT * 2 * 64) return;
    int lane = (int)(t & 63);
    long long rest = t >> 6;
    int nf = (int)(rest & 1); rest >>= 1;
    int kt = (int)(rest % KT); rest /= KT;
    int nt = (int)(rest % 64);
    int d  = (int)(rest / 64);
    int c = lane & 15, q = lane >> 4;
    int bc = nf * 16 + c;
    int r = (bc >> 3) * 512 + nt * 8 + (bc & 7);
    const float* src;
    if (kt < xKt) src = wih + ((long long)d * 2048 * xK + (long long)r * xK + kt * 32 + q * 8);
    else          src = whh + ((long long)d * 2048 * 512 + (long long)r * 512 + (kt - xKt) * 32 + q * 8);
    float4 v0 = *(const float4*)src;
    float4 v1 = *(const float4*)(src + 4);
    unsigned short o[8] = { f2b(v0.x), f2b(v0.y), f2b(v0.z), f2b(v0.w),
                            f2b(v1.x), f2b(v1.y), f2b(v1.z), f2b(v1.w) };
    *(uint4*)(wpack + t * 8) = *(const uint4*)o;
}

// ---------------------------------------------------------------------------
// Persistent BiLSTM, MFMA edition — batch-grouped partition.
//  - 256 blocks = 2 dir x 2 batch-group x 64 col-blocks. Each block owns
//    32 batch rows x 8 h-cols (32 gate cols). Batch rows are independent
//    sequences, so the h exchange only spans the 64 blocks of one (d,bg)
//    group: broadcast volume 16MB->8MB/step, coupling group 128->64.
//  - hbuf: [8 par][2 d][2 bg][64 nt][32 row][2 cq] u64, data-is-signal
//    poison scheme (a u64 of 4 bf16 h-values is never all-ones). Producer
//    publishes parity s&7 and re-poisons (s+2)&7 (own exclusive 512B).
//  - h prime-burst loads are issued BEFORE the X phase: IF read latency
//    hides under X compute; the poison-validate loop absorbs early reads.
//  - H-phase weights are LDS-resident (32KB, loaded once per layer):
//    no L2 latency/jitter on the post-wait critical path.
//  - Arithmetic (k-order per accumulator, reduction order, gate math) is
//    bit-identical to the previous passing kernel.
// ---------------------------------------------------------------------------
__global__ __launch_bounds__(256) void lstm_mfma(
    const int* __restrict__ tokens,
    const unsigned short* __restrict__ embB,   // [32000][512] bf16
    const unsigned short* __restrict__ wp0,    // packed L0 weights
    const unsigned short* __restrict__ wp1,    // packed L1 weights
    const float* __restrict__ bb0, const float* __restrict__ bb1,
    unsigned short* __restrict__ hs0,          // [T][B][1024] bf16
    unsigned short* __restrict__ hs1,
    unsigned long long* __restrict__ hbuf64,   // [8][2][2][64][32][2] u64
    unsigned int* __restrict__ flags)          // 256 x 32 u32 (128B pad/line)
{
    __shared__ uint4 wldsH[2048];              // 32KB: 16 kth x 2 nf x 64 lane
    __shared__ float Gred[4][32][33];
    __shared__ float hsh[32][9];
    __shared__ int   tok_s[32];

    const int bid = blockIdx.x;
    const int d   = bid >> 7;
    const int bg  = (bid >> 6) & 1;
    const int nt  = bid & 63;
    const int tid = threadIdx.x;
    const int w    = tid >> 6;
    const int lane = tid & 63;
    const int lm = lane & 15, q = lane >> 4;
    const int brow = tid >> 3, hc = tid & 7;   // gate-phase cell (row, hcol)

    float creg = 0.0f;

    for (int l = 0; l < 2; ++l) {
        const int xK  = l ? 1024 : 512;
        const int xKt = xK >> 5;
        const int KT  = xKt + 16;
        const int nX  = xKt >> 2;              // X-phase kts per wave
        const unsigned short* wp = (l ? wp1 : wp0) + (long long)(d * 64 + nt) * KT * 1024;
        const float* bia = (l ? bb1 : bb0) + (long long)d * 2048;
        unsigned short* hso = l ? hs1 : hs0;

        // H-phase weights -> LDS (once per layer)
        const uint4* wp4 = (const uint4*)wp;
        for (int j = tid; j < 2048; j += 256)
            wldsH[j] = wp4[xKt * 128 + j];

        float breg[4];
        #pragma unroll
        for (int g = 0; g < 4; ++g) breg[g] = bia[g * 512 + nt * 8 + hc];
        creg = 0.0f;
        __syncthreads();

        for (int s = 0; s < T_STEPS; ++s) {
            const int tt = d ? (T_STEPS - 1 - s) : s;

            if (l == 0 && tid < 32) tok_s[tid] = tokens[tt * BATCH + bg * 32 + tid];
            __syncthreads();

            // ---- prime-burst h(s-1) loads (validated later, hides IF lat) --
            HQ hq[4][2];
            const unsigned long long* hbq =
                hbuf64 + (long long)(((((s - 1) & 7) * 2 + d) * 2 + bg)) * 4096;
            if (s > 0) {
                #pragma unroll
                for (int i = 0; i < 4; ++i) {
                    const int kth = w * 4 + i;
                    #pragma unroll
                    for (int mt = 0; mt < 2; ++mt) {
                        const int base = (kth * 4 + q) * 64 + (mt * 16 + lm) * 2;
                        hq[i][mt].q[0] = __hip_atomic_load(hbq + base,     __ATOMIC_RELAXED, __HIP_MEMORY_SCOPE_AGENT);
                        hq[i][mt].q[1] = __hip_atomic_load(hbq + base + 1, __ATOMIC_RELAXED, __HIP_MEMORY_SCOPE_AGENT);
                    }
                }
            }

            f32x4 acc[2][2];
            #pragma unroll
            for (int mt = 0; mt < 2; ++mt)
                #pragma unroll
                for (int nf = 0; nf < 2; ++nf) acc[mt][nf] = (f32x4)0.0f;

            // A-row base pointers (lane rows mt*16+lm)
            const unsigned short* xr[2];
            #pragma unroll
            for (int mt = 0; mt < 2; ++mt) {
                int m = mt * 16 + lm;
                if (l == 0) xr[mt] = embB + (long long)tok_s[m] * 512;
                else        xr[mt] = hs0 + ((long long)tt * 64 + bg * 32 + m) * 1024;
            }

            // ---------------- X phase (no h dependency) ---------------------
            for (int i = 0; i < nX; ++i) {
                const int kt = w * nX + i;
                V16 av[2], bv[2];
                #pragma unroll
                for (int mt = 0; mt < 2; ++mt)
                    av[mt].u = *(const uint4*)(xr[mt] + kt * 32 + q * 8);
                #pragma unroll
                for (int nf = 0; nf < 2; ++nf)
                    bv[nf].u = *(const uint4*)(wp + ((long long)kt * 128 + nf * 64 + lane) * 8);
                #pragma unroll
                for (int mt = 0; mt < 2; ++mt)
                    #pragma unroll
                    for (int nf = 0; nf < 2; ++nf)
                        acc[mt][nf] = __builtin_amdgcn_mfma_f32_16x16x32_bf16(av[mt].s, bv[nf].s, acc[mt][nf], 0, 0, 0);
            }

            // ---------------- recurrent phase: validate then MFMA -----------
            if (s > 0) {
                int n = 0;
                for (;;) {
                    int bad = 0;
                    #pragma unroll
                    for (int i = 0; i < 4; ++i) {
                        const int kth = w * 4 + i;
                        #pragma unroll
                        for (int mt = 0; mt < 2; ++mt) {
                            const int base = (kth * 4 + q) * 64 + (mt * 16 + lm) * 2;
                            if (hq[i][mt].q[0] == POISON) {
                                hq[i][mt].q[0] = __hip_atomic_load(hbq + base,     __ATOMIC_RELAXED, __HIP_MEMORY_SCOPE_AGENT);
                                bad = 1;
                            }
                            if (hq[i][mt].q[1] == POISON) {
                                hq[i][mt].q[1] = __hip_atomic_load(hbq + base + 1, __ATOMIC_RELAXED, __HIP_MEMORY_SCOPE_AGENT);
                                bad = 1;
                            }
                        }
                    }
                    if (!bad) break;
                    __builtin_amdgcn_s_sleep(1);
                    if (++n > SPIN_LIM) break;
                }

                #pragma unroll
                for (int i = 0; i < 4; ++i) {
                    const int kth = w * 4 + i;
                    V16 bv[2];
                    #pragma unroll
                    for (int nf = 0; nf < 2; ++nf)
                        bv[nf].u = wldsH[(kth * 2 + nf) * 64 + lane];
                    #pragma unroll
                    for (int mt = 0; mt < 2; ++mt)
                        #pragma unroll
                        for (int nf = 0; nf < 2; ++nf)
                            acc[mt][nf] = __builtin_amdgcn_mfma_f32_16x16x32_bf16(hq[i][mt].s, bv[nf].s, acc[mt][nf], 0, 0, 0);
                }
            }

            // ---------------- K-reduce across waves + gates -----------------
            #pragma unroll
            for (int mt = 0; mt < 2; ++mt)
                #pragma unroll
                for (int nf = 0; nf < 2; ++nf)
                    #pragma unroll
                    for (int r = 0; r < 4; ++r)
                        Gred[w][nf * 16 + lm][mt * 16 + q * 4 + r] = acc[mt][nf][r];
            __syncthreads();

            float vg[4];
            #pragma unroll
            for (int g = 0; g < 4; ++g) {
                float v = breg[g];
                #pragma unroll
                for (int ww = 0; ww < 4; ++ww) v += Gred[ww][g * 8 + hc][brow];
                vg[g] = v;
            }
            const float si = 1.0f / (1.0f + __expf(-vg[0]));
            const float sf = 1.0f / (1.0f + __expf(-vg[1]));
            const float so = 1.0f / (1.0f + __expf(-vg[3]));
            const float cn = sf * creg + si * tanhf(vg[2]);
            const float hn = so * tanhf(cn);
            creg = cn;
            hsh[brow][hc] = hn;
            __syncthreads();

            // ------- publish h (data store IS the signal) + poison ahead ----
            if (tid < 64) {
                const int row = tid >> 1, cq = tid & 1;
                unsigned long long hv =
                      (unsigned long long)f2b(hsh[row][cq * 4 + 0])
                    | ((unsigned long long)f2b(hsh[row][cq * 4 + 1]) << 16)
                    | ((unsigned long long)f2b(hsh[row][cq * 4 + 2]) << 32)
                    | ((unsigned long long)f2b(hsh[row][cq * 4 + 3]) << 48);
                unsigned long long* dst =
                    hbuf64 + ((long long)((((s & 7) * 2 + d) * 2 + bg) * 64 + nt)) * 64 + tid;
                __hip_atomic_store(dst, hv, __ATOMIC_RELAXED, __HIP_MEMORY_SCOPE_AGENT);
                *(unsigned long long*)(hso + ((long long)tt * 64 + bg * 32 + row) * 1024
                                           + d * 512 + nt * 8 + cq * 4) = hv;
                unsigned long long* pdst =
                    hbuf64 + ((long long)(((((s + 2) & 7) * 2 + d) * 2 + bg) * 64 + nt)) * 64 + tid;
                __hip_atomic_store(pdst, POISON, __ATOMIC_RELAXED, __HIP_MEMORY_SCOPE_AGENT);
            }
            // no per-step drain / flag / barrier: consumers self-validate
        }

        // ------------- layer boundary: two-phase barrier --------------------
        if (l == 0) {
            __threadfence();                    // wb dirty hs0 out of local L2
            __syncthreads();
            if (tid == 0)
                __hip_atomic_store(flags + bid * 32, LAYER_DONE,
                                   __ATOMIC_RELAXED, __HIP_MEMORY_SCOPE_AGENT);
            if (tid < 64) {                     // phase 1: all 256 blocks done
                int n = 0;
                for (;;) {
                    unsigned a = __hip_atomic_load(flags + tid * 32,         __ATOMIC_RELAXED, __HIP_MEMORY_SCOPE_AGENT);
                    unsigned b = __hip_atomic_load(flags + (tid + 64) * 32,  __ATOMIC_RELAXED, __HIP_MEMORY_SCOPE_AGENT);
                    unsigned c = __hip_atomic_load(flags + (tid + 128) * 32, __ATOMIC_RELAXED, __HIP_MEMORY_SCOPE_AGENT);
                    unsigned e = __hip_atomic_load(flags + (tid + 192) * 32, __ATOMIC_RELAXED, __HIP_MEMORY_SCOPE_AGENT);
                    if (__all(a >= LAYER_DONE && b >= LAYER_DONE &&
                              c >= LAYER_DONE && e >= LAYER_DONE)) break;
                    __builtin_amdgcn_s_sleep(1);
                    if (++n > SPIN_LIM) break;
                }
            }
            __syncthreads();
            if (tid < 64) {                     // re-poison all parities (own region)
                #pragma unroll
                for (int p = 0; p < 8; ++p) {
                    unsigned long long* pd =
                        hbuf64 + ((long long)(((p * 2 + d) * 2 + bg) * 64 + nt)) * 64 + tid;
                    __hip_atomic_store(pd, POISON, __ATOMIC_RELAXED, __HIP_MEMORY_SCOPE_AGENT);
                }
            }
            asm volatile("s_waitcnt vmcnt(0)" ::: "memory");
            __syncthreads();
            if (tid == 0)
                __hip_atomic_store(flags + bid * 32, POISON_DONE,
                                   __ATOMIC_RELAXED, __HIP_MEMORY_SCOPE_AGENT);
            if (tid < 64) {                     // phase 2: all poisons visible
                int n = 0;
                for (;;) {
                    unsigned a = __hip_atomic_load(flags + tid * 32,         __ATOMIC_RELAXED, __HIP_MEMORY_SCOPE_AGENT);
                    unsigned b = __hip_atomic_load(flags + (tid + 64) * 32,  __ATOMIC_RELAXED, __HIP_MEMORY_SCOPE_AGENT);
                    unsigned c = __hip_atomic_load(flags + (tid + 128) * 32, __ATOMIC_RELAXED, __HIP_MEMORY_SCOPE_AGENT);
                    unsigned e = __hip_atomic_load(flags + (tid + 192) * 32, __ATOMIC_RELAXED, __HIP_MEMORY_SCOPE_AGENT);
                    if (__all(a >= POISON_DONE && b >= POISON_DONE &&
                              c >= POISON_DONE && e >= POISON_DONE)) break;
                    __builtin_amdgcn_s_sleep(1);
                    if (++n > SPIN_LIM) break;
                }
            }
            __syncthreads();
            __threadfence();                    // inv stale lines before cached reads
        }
    }
}

// ---------------------------------------------------------------------------
// feats = hs1(bf16) @ lin_w^T + lin_b   (64-row tiles, N=32)
// ---------------------------------------------------------------------------
__global__ __launch_bounds__(256) void gemm_feats(
    const unsigned short* __restrict__ A,      // [M][1024] bf16
    const float* __restrict__ W,               // [32][1024]
    const float* __restrict__ bias,
    float* __restrict__ C,
    int M, int N, int K)
{
    __shared__ __align__(16) float As[64][34];
    __shared__ __align__(16) float Ws[32][68];

    const int m0 = blockIdx.y * 64;
    const int tid = threadIdx.x;
    const int tr = tid >> 4;
    const int tc = tid & 15;

    float acc[4][4];
    #pragma unroll
    for (int i = 0; i < 4; ++i)
        #pragma unroll
        for (int j = 0; j < 4; ++j) acc[i][j] = 0.0f;

    for (int k0 = 0; k0 < K; k0 += 32) {
        {   // A tile: 64 rows x 32 k (bf16 -> f32)
            int row = tid >> 2, g8 = tid & 3;
            uint4 v = *(const uint4*)(A + ((long long)(m0 + row)) * 1024 + k0 + g8 * 8);
            const unsigned short* pv = (const unsigned short*)&v;
            #pragma unroll
            for (int e = 0; e < 8; ++e) As[row][g8 * 8 + e] = b2f(pv[e]);
        }
        {   // W tile: 32 rows x 32 k, transposed
            int row = tid >> 3, q2 = tid & 7;
            float4 v = *(const float4*)(W + (long long)row * K + k0 + 4 * q2);
            Ws[4*q2+0][row] = v.x; Ws[4*q2+1][row] = v.y;
            Ws[4*q2+2][row] = v.z; Ws[4*q2+3][row] = v.w;
        }
        __syncthreads();
        #pragma unroll 8
        for (int kk = 0; kk < 32; ++kk) {
            float a0 = As[4*tr+0][kk], a1 = As[4*tr+1][kk];
            float a2 = As[4*tr+2][kk], a3 = As[4*tr+3][kk];
            float4 wv = *(const float4*)&Ws[kk][4*tc];
            acc[0][0] += a0*wv.x; acc[0][1] += a0*wv.y; acc[0][2] += a0*wv.z; acc[0][3] += a0*wv.w;
            acc[1][0] += a1*wv.x; acc[1][1] += a1*wv.y; acc[1][2] += a1*wv.z; acc[1][3] += a1*wv.w;
            acc[2][0] += a2*wv.x; acc[2][1] += a2*wv.y; acc[2][2] += a2*wv.z; acc[2][3] += a2*wv.w;
            acc[3][0] += a3*wv.x; acc[3][1] += a3*wv.y; acc[3][2] += a3*wv.z; acc[3][3] += a3*wv.w;
        }
        __syncthreads();
    }
    #pragma unroll
    for (int i = 0; i < 4; ++i) {
        int m = m0 + 4*tr + i;
        #pragma unroll
        for (int j = 0; j < 4; ++j) {
            int n = 4*tc + j;
            if (n < N) C[(long long)m * N + n] = acc[i][j] + bias[n];
        }
    }
}

// ---------------------------------------------------------------------------
// CRF: forward logsumexp scan + log_z + gold score + loss, one block per b.
// ---------------------------------------------------------------------------
__global__ __launch_bounds__(1024) void crf_kernel(
    const float* __restrict__ feats,
    const float* __restrict__ trans,
    const int*   __restrict__ tokens,
    const int*   __restrict__ tags,
    const int*   __restrict__ lengths,
    float* __restrict__ out)
{
    const int b = blockIdx.x;
    const int tid = threadIdx.x;
    __shared__ float tr_s[KTAGS*KTAGS];
    __shared__ float score_s[KTAGS];
    __shared__ float emit_s[KTAGS];
    __shared__ float red_s[16];
    __shared__ float logz_s;

    tr_s[tid] = trans[tid];
    if (tid < KTAGS) score_s[tid] = (tid == START_TAG) ? 0.0f : NEGV;
    __syncthreads();

    const int i = tid >> 5, j = tid & 31;
    for (int t = 0; t < T_STEPS; ++t) {
        if (tid < KTAGS) emit_s[tid] = feats[((long long)t*BATCH + b)*KTAGS + tid];
        __syncthreads();
        float e = score_s[j] + tr_s[i*KTAGS + j];
        float m = e;
        m = fmaxf(m, __shfl_xor(m, 1));  m = fmaxf(m, __shfl_xor(m, 2));
        m = fmaxf(m, __shfl_xor(m, 4));  m = fmaxf(m, __shfl_xor(m, 8));
        m = fmaxf(m, __shfl_xor(m, 16));
        float p = __expf(e - m);
        p += __shfl_xor(p, 1); p += __shfl_xor(p, 2); p += __shfl_xor(p, 4);
        p += __shfl_xor(p, 8); p += __shfl_xor(p, 16);
        float nv = m + __logf(p) + emit_s[i];
        int msk = tokens[(long long)t*BATCH + b] > 0;
        __syncthreads();
        if (j == 0) score_s[i] = msk ? nv : score_s[i];
        __syncthreads();
    }

    if (tid < KTAGS) {
        float v = score_s[tid] + tr_s[END_TAG*KTAGS + tid];
        float m = v;
        m = fmaxf(m, __shfl_xor(m, 1));  m = fmaxf(m, __shfl_xor(m, 2));
        m = fmaxf(m, __shfl_xor(m, 4));  m = fmaxf(m, __shfl_xor(m, 8));
        m = fmaxf(m, __shfl_xor(m, 16));
        float p = __expf(v - m);
        p += __shfl_xor(p, 1); p += __shfl_xor(p, 2); p += __shfl_xor(p, 4);
        p += __shfl_xor(p, 8); p += __shfl_xor(p, 16);
        if (tid == 0) logz_s = m + __logf(p);
    }
    __syncthreads();

    float val = 0.0f;
    if (tid < T_STEPS) {
        int t = tid;
        int cur  = tags[(long long)t*BATCH + b];
        int prev = (t == 0) ? START_TAG : tags[(long long)(t-1)*BATCH + b];
        int msk  = tokens[(long long)t*BATCH + b] > 0;
        if (msk) val = tr_s[cur*KTAGS + prev]
                     + feats[((long long)t*BATCH + b)*KTAGS + cur];
    }
    val += __shfl_xor(val, 1);  val += __shfl_xor(val, 2);
    val += __shfl_xor(val, 4);  val += __shfl_xor(val, 8);
    val += __shfl_xor(val, 16); val += __shfl_xor(val, 32);
    int wave = tid >> 6, lane = tid & 63;
    if (lane == 0) red_s[wave] = val;
    __syncthreads();
    if (tid == 0) {
        float g = 0.0f;
        #pragma unroll
        for (int w = 0; w < 16; ++w) g += red_s[w];
        g += tr_s[END_TAG*KTAGS + tags[(long long)(T_STEPS-1)*BATCH + b]];
        atomicAdd(out, (logz_s - g) / (float)lengths[b]);
    }
}

// ---------------------------------------------------------------------------
extern "C" void kernel_launch(void* const* d_in, const int* in_sizes, int n_in,
                              void* d_out, int out_size, void* d_ws, size_t ws_size,
                              hipStream_t stream) {
    const int*   tokens  = (const int*)  d_in[0];
    const int*   tags    = (const int*)  d_in[1];
    const int*   lengths = (const int*)  d_in[2];
    const float* embed   = (const float*)d_in[3];
    const float* wih0    = (const float*)d_in[4];
    const float* whh0    = (const float*)d_in[5];
    const float* b0      = (const float*)d_in[6];
    const float* wih1    = (const float*)d_in[7];
    const float* whh1    = (const float*)d_in[8];
    const float* b1      = (const float*)d_in[9];
    const float* lin_w   = (const float*)d_in[10];
    const float* lin_b   = (const float*)d_in[11];
    const float* trans   = (const float*)d_in[12];

    // Workspace layout (total ~123.2 MiB footprint, unchanged).
    // Flags (64 KiB) and the 8-parity h-exchange buffers (1 MiB) live INSIDE
    // the feats buffer (2 MiB): feats is dead until gemm_feats runs (after
    // lstm_mfma completes), and gemm overwrites the whole 2 MiB.
    char* ws = (char*)d_ws;
    unsigned short* hs0   = (unsigned short*)(ws);                   // 33,554,432
    unsigned short* hs1   = (unsigned short*)(ws +  33554432ULL);    // 33,554,432
    unsigned short* embB  = (unsigned short*)(ws +  67108864ULL);    // 32,768,000
    unsigned short* wp0   = (unsigned short*)(ws +  99876864ULL);    //  8,388,608
    unsigned short* wp1   = (unsigned short*)(ws + 108265472ULL);    // 12,582,912
    float*          feats = (float*)        (ws + 120848384ULL);     //  2,097,152
    unsigned int*   flagsP = (unsigned int*)feats;                   // 65,536
    unsigned long long* hbufP = (unsigned long long*)((char*)feats + 65536); // 1,048,576

    float* out = (float*)d_out;

    init_zero<<<dim3(512), 256, 0, stream>>>(flagsP, hbufP, out);
    convert_embed<<<dim3(16000), 256, 0, stream>>>(embed, embB);
    pack_w<<<dim3(2048), 256, 0, stream>>>(wih0, whh0, 512,  wp0);
    pack_w<<<dim3(3072), 256, 0, stream>>>(wih1, whh1, 1024, wp1);

    lstm_mfma<<<dim3(NBLK), 256, 0, stream>>>(
        tokens, embB, wp0, wp1, b0, b1, hs0, hs1, hbufP, flagsP);

    gemm_feats<<<dim3(1, 256, 1), 256, 0, stream>>>(
        hs1, lin_w, lin_b, feats, T_STEPS*BATCH, KTAGS, 2*HID);

    crf_kernel<<<dim3(BATCH), 1024, 0, stream>>>(feats, trans, tokens, tags,
                                                 lengths, out);
}

// Round 5
// 2423.732 us; speedup vs baseline: 2.3106x; 1.1796x over previous
//
#include <hip/hip_runtime.h>
#include <math.h>

// Problem constants (V,E,H,K,T,B) = (32000, 512, 512, 32, 256, 64)
#define T_STEPS 256
#define BATCH   64
#define HID     512
#define KTAGS   32
#define NEGV    -100000.0f
#define START_TAG 30
#define END_TAG   31

#define NBLK      256
#define SPIN_LIM  (1 << 26)
#define LAYER_DONE  300u
#define POISON_DONE 301u
#define POISON    0xFFFFFFFFFFFFFFFFULL

typedef __attribute__((ext_vector_type(8))) short short8;
typedef __attribute__((ext_vector_type(4))) float f32x4;

union V16 { uint4 u; short8 s; };
union HQ  { unsigned long long q[2]; short8 s; };

static __device__ __forceinline__ unsigned short f2b(float f) {
    unsigned u = __float_as_uint(f);
    return (unsigned short)((u + 0x7fffu + ((u >> 16) & 1u)) >> 16);
}
static __device__ __forceinline__ float b2f(unsigned short us) {
    return __uint_as_float(((unsigned)us) << 16);
}

// ---------------------------------------------------------------------------
// Init: poison h-exchange buffers (8 par x 2 d x 2 bg x 64 nt x 64 u64 = 1MB),
// zero padded flag region, zero d_out. Agent-scope stores.
// ---------------------------------------------------------------------------
__global__ __launch_bounds__(256) void init_zero(unsigned int* __restrict__ flags,
                                                 unsigned long long* __restrict__ hbuf,
                                                 float* __restrict__ out)
{
    int i = blockIdx.x * 256 + threadIdx.x;
    if (i < 131072)
        __hip_atomic_store(hbuf + i, POISON, __ATOMIC_RELAXED, __HIP_MEMORY_SCOPE_AGENT);
    if (i < 16384)
        __hip_atomic_store(flags + i, 0u, __ATOMIC_RELAXED, __HIP_MEMORY_SCOPE_AGENT);
    if (i == 0)
        __hip_atomic_store(out, 0.0f, __ATOMIC_RELAXED, __HIP_MEMORY_SCOPE_AGENT);
}

// ---------------------------------------------------------------------------
// embed fp32 -> bf16 (one-time, 16.4M elements)
// ---------------------------------------------------------------------------
__global__ __launch_bounds__(256) void convert_embed(const float* __restrict__ src,
                                                     unsigned short* __restrict__ dst)
{
    long long i = ((long long)blockIdx.x * 256 + threadIdx.x) * 4;
    if (i >= (long long)32000 * 512) return;
    float4 v = *(const float4*)(src + i);
    ushort4 o;
    o.x = f2b(v.x); o.y = f2b(v.y); o.z = f2b(v.z); o.w = f2b(v.w);
    *(ushort4*)(dst + i) = o;
}

// ---------------------------------------------------------------------------
// Pack Wih|Whh (fp32) into bf16 MFMA B-fragment stream for the
// 64-col-block partition. Stream: [d][nt(64)][kt(KT)][nf(2)][lane(64)][j(8)].
// Block (d,nt) owns h-cols nt*8..nt*8+7 => 32 gate cols; frag nf covers
// block-cols bc = nf*16 + (lane&15), bc -> gate g = bc>>3, cc = bc&7,
// weight row r = g*512 + nt*8 + cc; k = kt*32 + (lane>>4)*8 + j.
// kt<xKt -> Wih, else Whh. Thread t == flat 16B granule => coalesced stores.
// ---------------------------------------------------------------------------
__global__ __launch_bounds__(256) void pack_w(const float* __restrict__ wih,
                                              const float* __restrict__ whh,
                                              int xK,
                                              unsigned short* __restrict__ wpack)
{
    const int xKt = xK >> 5, KT = xKt + 16;
    long long t = (long long)blockIdx.x * 256 + threadIdx.x;
    if (t >= (long long)2 * 64 * KT * 2 * 64) return;
    int lane = (int)(t & 63);
    long long rest = t >> 6;
    int nf = (int)(rest & 1); rest >>= 1;
    int kt = (int)(rest % KT); rest /= KT;
    int nt = (int)(rest % 64);
    int d  = (int)(rest / 64);
    int c = lane & 15, q = lane >> 4;
    int bc = nf * 16 + c;
    int r = (bc >> 3) * 512 + nt * 8 + (bc & 7);
    const float* src;
    if (kt < xKt) src = wih + ((long long)d * 2048 * xK + (long long)r * xK + kt * 32 + q * 8);
    else          src = whh + ((long long)d * 2048 * 512 + (long long)r * 512 + (kt - xKt) * 32 + q * 8);
    float4 v0 = *(const float4*)src;
    float4 v1 = *(const float4*)(src + 4);
    unsigned short o[8] = { f2b(v0.x), f2b(v0.y), f2b(v0.z), f2b(v0.w),
                            f2b(v1.x), f2b(v1.y), f2b(v1.z), f2b(v1.w) };
    *(uint4*)(wpack + t * 8) = *(const uint4*)o;
}

// ---------------------------------------------------------------------------
// One BiLSTM layer's step loop, templated on input width XK so the X phase
// fully unrolls. Load-issue order per step (vmcnt FIFO is in-order retire):
//   [all X-phase A/B loads] -> [16 prime-burst h loads] -> [X MFMAs (wait
//   vmcnt leaves primes in flight)] -> [validate primes] -> [H MFMAs].
// Publish packs h via shfl_xor (lanes hc^1,hc^2) — no hsh LDS, no 3rd
// barrier. All arithmetic (k-order per acc, reduce order, gate math, pack
// bit layout, store addresses, atomic scopes) identical to prior version.
// ---------------------------------------------------------------------------
template<int XK>
static __device__ __forceinline__ void layer_steps(
    const int d, const int bg, const int nt, const int tid,
    const int* __restrict__ tokens,
    const unsigned short* __restrict__ embB,
    const unsigned short* __restrict__ hs_in,   // L1 input rows (null for L0)
    const unsigned short* __restrict__ wp,      // block's packed weight base
    const float* __restrict__ bia,
    unsigned short* __restrict__ hso,
    unsigned long long* __restrict__ hbuf64,
    uint4* __restrict__ wldsH,
    float (&Gred)[4][32][33],
    int* __restrict__ tok_s)
{
    constexpr bool L0  = (XK == 512);
    constexpr int  xKt = XK >> 5;
    constexpr int  nX  = xKt >> 2;             // X-phase kts per wave (4 or 8)

    const int w = tid >> 6, lane = tid & 63;
    const int lm = lane & 15, q = lane >> 4;
    const int brow = tid >> 3, hc = tid & 7;   // gate-phase cell (row, hcol)

    // H-phase weights -> LDS (once per layer)
    const uint4* wp4 = (const uint4*)wp;
    for (int j = tid; j < 2048; j += 256)
        wldsH[j] = wp4[xKt * 128 + j];

    float breg[4];
    #pragma unroll
    for (int g = 0; g < 4; ++g) breg[g] = bia[g * 512 + nt * 8 + hc];
    float creg = 0.0f;

    __syncthreads();

    for (int s = 0; s < T_STEPS; ++s) {
        const int tt = d ? (T_STEPS - 1 - s) : s;

        if (L0 && tid < 32) tok_s[tid] = tokens[tt * BATCH + bg * 32 + tid];
        __syncthreads();                       // tok ready + Gred WAR

        // A-row base pointers (lane rows mt*16+lm)
        const unsigned short* xr[2];
        #pragma unroll
        for (int mt = 0; mt < 2; ++mt) {
            int m = mt * 16 + lm;
            if (L0) xr[mt] = embB + (long long)tok_s[m] * 512;
            else    xr[mt] = hs_in + ((long long)tt * 64 + bg * 32 + m) * 1024;
        }

        // ---------------- issue ALL X loads (unrolled, in flight) ----------
        uint4 av[nX][2], bv[nX][2];
        #pragma unroll
        for (int i = 0; i < nX; ++i) {
            const int kt = w * nX + i;
            #pragma unroll
            for (int mt = 0; mt < 2; ++mt)
                av[i][mt] = *(const uint4*)(xr[mt] + kt * 32 + q * 8);
            #pragma unroll
            for (int nf = 0; nf < 2; ++nf)
                bv[i][nf] = *(const uint4*)(wp + ((long long)kt * 128 + nf * 64 + lane) * 8);
        }

        // ---------------- prime-burst h(s-1) (after X loads in FIFO) -------
        HQ hq[4][2];
        const unsigned long long* hbq =
            hbuf64 + (long long)(((((s - 1) & 7) * 2 + d) * 2 + bg)) * 4096;
        if (s > 0) {
            #pragma unroll
            for (int i = 0; i < 4; ++i) {
                const int kth = w * 4 + i;
                #pragma unroll
                for (int mt = 0; mt < 2; ++mt) {
                    const int base = (kth * 4 + q) * 64 + (mt * 16 + lm) * 2;
                    hq[i][mt].q[0] = __hip_atomic_load(hbq + base,     __ATOMIC_RELAXED, __HIP_MEMORY_SCOPE_AGENT);
                    hq[i][mt].q[1] = __hip_atomic_load(hbq + base + 1, __ATOMIC_RELAXED, __HIP_MEMORY_SCOPE_AGENT);
                }
            }
        }

        // ---------------- X MFMAs (primes stay in flight) ------------------
        f32x4 acc[2][2];
        #pragma unroll
        for (int mt = 0; mt < 2; ++mt)
            #pragma unroll
            for (int nf = 0; nf < 2; ++nf) acc[mt][nf] = (f32x4)0.0f;

        #pragma unroll
        for (int i = 0; i < nX; ++i) {
            V16 a0, a1, b0, b1;
            a0.u = av[i][0]; a1.u = av[i][1];
            b0.u = bv[i][0]; b1.u = bv[i][1];
            acc[0][0] = __builtin_amdgcn_mfma_f32_16x16x32_bf16(a0.s, b0.s, acc[0][0], 0, 0, 0);
            acc[0][1] = __builtin_amdgcn_mfma_f32_16x16x32_bf16(a0.s, b1.s, acc[0][1], 0, 0, 0);
            acc[1][0] = __builtin_amdgcn_mfma_f32_16x16x32_bf16(a1.s, b0.s, acc[1][0], 0, 0, 0);
            acc[1][1] = __builtin_amdgcn_mfma_f32_16x16x32_bf16(a1.s, b1.s, acc[1][1], 0, 0, 0);
        }

        // ---------------- validate primes, then H MFMAs --------------------
        if (s > 0) {
            int n = 0;
            for (;;) {
                int bad = 0;
                #pragma unroll
                for (int i = 0; i < 4; ++i) {
                    const int kth = w * 4 + i;
                    #pragma unroll
                    for (int mt = 0; mt < 2; ++mt) {
                        const int base = (kth * 4 + q) * 64 + (mt * 16 + lm) * 2;
                        if (hq[i][mt].q[0] == POISON) {
                            hq[i][mt].q[0] = __hip_atomic_load(hbq + base,     __ATOMIC_RELAXED, __HIP_MEMORY_SCOPE_AGENT);
                            bad = 1;
                        }
                        if (hq[i][mt].q[1] == POISON) {
                            hq[i][mt].q[1] = __hip_atomic_load(hbq + base + 1, __ATOMIC_RELAXED, __HIP_MEMORY_SCOPE_AGENT);
                            bad = 1;
                        }
                    }
                }
                if (!bad) break;
                __builtin_amdgcn_s_sleep(1);
                if (++n > SPIN_LIM) break;
            }

            #pragma unroll
            for (int i = 0; i < 4; ++i) {
                const int kth = w * 4 + i;
                V16 b0, b1;
                b0.u = wldsH[(kth * 2 + 0) * 64 + lane];
                b1.u = wldsH[(kth * 2 + 1) * 64 + lane];
                acc[0][0] = __builtin_amdgcn_mfma_f32_16x16x32_bf16(hq[i][0].s, b0.s, acc[0][0], 0, 0, 0);
                acc[0][1] = __builtin_amdgcn_mfma_f32_16x16x32_bf16(hq[i][0].s, b1.s, acc[0][1], 0, 0, 0);
                acc[1][0] = __builtin_amdgcn_mfma_f32_16x16x32_bf16(hq[i][1].s, b0.s, acc[1][0], 0, 0, 0);
                acc[1][1] = __builtin_amdgcn_mfma_f32_16x16x32_bf16(hq[i][1].s, b1.s, acc[1][1], 0, 0, 0);
            }
        }

        // ---------------- K-reduce across waves + gates ---------------------
        #pragma unroll
        for (int mt = 0; mt < 2; ++mt)
            #pragma unroll
            for (int nf = 0; nf < 2; ++nf)
                #pragma unroll
                for (int r = 0; r < 4; ++r)
                    Gred[w][nf * 16 + lm][mt * 16 + q * 4 + r] = acc[mt][nf][r];
        __syncthreads();

        float vg[4];
        #pragma unroll
        for (int g = 0; g < 4; ++g) {
            float v = breg[g];
            #pragma unroll
            for (int ww = 0; ww < 4; ++ww) v += Gred[ww][g * 8 + hc][brow];
            vg[g] = v;
        }
        const float si = 1.0f / (1.0f + __expf(-vg[0]));
        const float sf = 1.0f / (1.0f + __expf(-vg[1]));
        const float so = 1.0f / (1.0f + __expf(-vg[3]));
        const float cn = sf * creg + si * tanhf(vg[2]);
        const float hn = so * tanhf(cn);
        creg = cn;

        // ------- publish h via shfl pack (data store IS the signal) --------
        unsigned pv = (unsigned)f2b(hn);
        unsigned p2 = pv | (__shfl_xor(pv, 1) << 16);
        unsigned long long hv = (unsigned long long)p2
                              | ((unsigned long long)__shfl_xor(p2, 2) << 32);
        if ((tid & 3) == 0) {
            const int row = brow, cq = hc >> 2;
            unsigned long long* dst =
                hbuf64 + ((long long)((((s & 7) * 2 + d) * 2 + bg) * 64 + nt)) * 64 + row * 2 + cq;
            __hip_atomic_store(dst, hv, __ATOMIC_RELAXED, __HIP_MEMORY_SCOPE_AGENT);
            *(unsigned long long*)(hso + ((long long)tt * 64 + bg * 32 + row) * 1024
                                       + d * 512 + nt * 8 + cq * 4) = hv;
            unsigned long long* pdst =
                hbuf64 + ((long long)(((((s + 2) & 7) * 2 + d) * 2 + bg) * 64 + nt)) * 64 + row * 2 + cq;
            __hip_atomic_store(pdst, POISON, __ATOMIC_RELAXED, __HIP_MEMORY_SCOPE_AGENT);
        }
        // no per-step drain / flag / 3rd barrier: consumers self-validate
    }
}

// ---------------------------------------------------------------------------
// Persistent BiLSTM, MFMA edition — batch-grouped partition (2d x 2bg x 64nt,
// block owns 32 rows x 8 h-cols), data-is-signal poison exchange, templated
// unrolled step loop. Layer boundary: two-phase flag barrier + re-poison.
// ---------------------------------------------------------------------------
__global__ __launch_bounds__(256, 1) void lstm_mfma(
    const int* __restrict__ tokens,
    const unsigned short* __restrict__ embB,   // [32000][512] bf16
    const unsigned short* __restrict__ wp0,    // packed L0 weights
    const unsigned short* __restrict__ wp1,    // packed L1 weights
    const float* __restrict__ bb0, const float* __restrict__ bb1,
    unsigned short* __restrict__ hs0,          // [T][B][1024] bf16
    unsigned short* __restrict__ hs1,
    unsigned long long* __restrict__ hbuf64,   // [8][2][2][64][32][2] u64
    unsigned int* __restrict__ flags)          // 256 x 32 u32 (128B pad/line)
{
    __shared__ uint4 wldsH[2048];              // 32KB: 16 kth x 2 nf x 64 lane
    __shared__ float Gred[4][32][33];
    __shared__ int   tok_s[32];

    const int bid = blockIdx.x;
    const int d   = bid >> 7;
    const int bg  = (bid >> 6) & 1;
    const int nt  = bid & 63;
    const int tid = threadIdx.x;

    layer_steps<512>(d, bg, nt, tid, tokens, embB, (const unsigned short*)nullptr,
                     wp0 + (long long)(d * 64 + nt) * 32 * 1024,
                     bb0 + (long long)d * 2048,
                     hs0, hbuf64, wldsH, Gred, tok_s);

    // ------------- layer boundary: two-phase barrier ------------------------
    {
        __threadfence();                    // wb dirty hs0 out of local L2
        __syncthreads();
        if (tid == 0)
            __hip_atomic_store(flags + bid * 32, LAYER_DONE,
                               __ATOMIC_RELAXED, __HIP_MEMORY_SCOPE_AGENT);
        if (tid < 64) {                     // phase 1: all 256 blocks done
            int n = 0;
            for (;;) {
                unsigned a = __hip_atomic_load(flags + tid * 32,         __ATOMIC_RELAXED, __HIP_MEMORY_SCOPE_AGENT);
                unsigned b = __hip_atomic_load(flags + (tid + 64) * 32,  __ATOMIC_RELAXED, __HIP_MEMORY_SCOPE_AGENT);
                unsigned c = __hip_atomic_load(flags + (tid + 128) * 32, __ATOMIC_RELAXED, __HIP_MEMORY_SCOPE_AGENT);
                unsigned e = __hip_atomic_load(flags + (tid + 192) * 32, __ATOMIC_RELAXED, __HIP_MEMORY_SCOPE_AGENT);
                if (__all(a >= LAYER_DONE && b >= LAYER_DONE &&
                          c >= LAYER_DONE && e >= LAYER_DONE)) break;
                __builtin_amdgcn_s_sleep(1);
                if (++n > SPIN_LIM) break;
            }
        }
        __syncthreads();
        if (tid < 64) {                     // re-poison all parities (own region)
            #pragma unroll
            for (int p = 0; p < 8; ++p) {
                unsigned long long* pd =
                    hbuf64 + ((long long)(((p * 2 + d) * 2 + bg) * 64 + nt)) * 64 + tid;
                __hip_atomic_store(pd, POISON, __ATOMIC_RELAXED, __HIP_MEMORY_SCOPE_AGENT);
            }
        }
        asm volatile("s_waitcnt vmcnt(0)" ::: "memory");
        __syncthreads();
        if (tid == 0)
            __hip_atomic_store(flags + bid * 32, POISON_DONE,
                               __ATOMIC_RELAXED, __HIP_MEMORY_SCOPE_AGENT);
        if (tid < 64) {                     // phase 2: all poisons visible
            int n = 0;
            for (;;) {
                unsigned a = __hip_atomic_load(flags + tid * 32,         __ATOMIC_RELAXED, __HIP_MEMORY_SCOPE_AGENT);
                unsigned b = __hip_atomic_load(flags + (tid + 64) * 32,  __ATOMIC_RELAXED, __HIP_MEMORY_SCOPE_AGENT);
                unsigned c = __hip_atomic_load(flags + (tid + 128) * 32, __ATOMIC_RELAXED, __HIP_MEMORY_SCOPE_AGENT);
                unsigned e = __hip_atomic_load(flags + (tid + 192) * 32, __ATOMIC_RELAXED, __HIP_MEMORY_SCOPE_AGENT);
                if (__all(a >= POISON_DONE && b >= POISON_DONE &&
                          c >= POISON_DONE && e >= POISON_DONE)) break;
                __builtin_amdgcn_s_sleep(1);
                if (++n > SPIN_LIM) break;
            }
        }
        __syncthreads();
        __threadfence();                    // inv stale lines before cached reads
    }

    layer_steps<1024>(d, bg, nt, tid, tokens, embB, hs0,
                      wp1 + (long long)(d * 64 + nt) * 48 * 1024,
                      bb1 + (long long)d * 2048,
                      hs1, hbuf64, wldsH, Gred, tok_s);
}

// ---------------------------------------------------------------------------
// feats = hs1(bf16) @ lin_w^T + lin_b   (64-row tiles, N=32)
// ---------------------------------------------------------------------------
__global__ __launch_bounds__(256) void gemm_feats(
    const unsigned short* __restrict__ A,      // [M][1024] bf16
    const float* __restrict__ W,               // [32][1024]
    const float* __restrict__ bias,
    float* __restrict__ C,
    int M, int N, int K)
{
    __shared__ __align__(16) float As[64][34];
    __shared__ __align__(16) float Ws[32][68];

    const int m0 = blockIdx.y * 64;
    const int tid = threadIdx.x;
    const int tr = tid >> 4;
    const int tc = tid & 15;

    float acc[4][4];
    #pragma unroll
    for (int i = 0; i < 4; ++i)
        #pragma unroll
        for (int j = 0; j < 4; ++j) acc[i][j] = 0.0f;

    for (int k0 = 0; k0 < K; k0 += 32) {
        {   // A tile: 64 rows x 32 k (bf16 -> f32)
            int row = tid >> 2, g8 = tid & 3;
            uint4 v = *(const uint4*)(A + ((long long)(m0 + row)) * 1024 + k0 + g8 * 8);
            const unsigned short* pv = (const unsigned short*)&v;
            #pragma unroll
            for (int e = 0; e < 8; ++e) As[row][g8 * 8 + e] = b2f(pv[e]);
        }
        {   // W tile: 32 rows x 32 k, transposed
            int row = tid >> 3, q2 = tid & 7;
            float4 v = *(const float4*)(W + (long long)row * K + k0 + 4 * q2);
            Ws[4*q2+0][row] = v.x; Ws[4*q2+1][row] = v.y;
            Ws[4*q2+2][row] = v.z; Ws[4*q2+3][row] = v.w;
        }
        __syncthreads();
        #pragma unroll 8
        for (int kk = 0; kk < 32; ++kk) {
            float a0 = As[4*tr+0][kk], a1 = As[4*tr+1][kk];
            float a2 = As[4*tr+2][kk], a3 = As[4*tr+3][kk];
            float4 wv = *(const float4*)&Ws[kk][4*tc];
            acc[0][0] += a0*wv.x; acc[0][1] += a0*wv.y; acc[0][2] += a0*wv.z; acc[0][3] += a0*wv.w;
            acc[1][0] += a1*wv.x; acc[1][1] += a1*wv.y; acc[1][2] += a1*wv.z; acc[1][3] += a1*wv.w;
            acc[2][0] += a2*wv.x; acc[2][1] += a2*wv.y; acc[2][2] += a2*wv.z; acc[2][3] += a2*wv.w;
            acc[3][0] += a3*wv.x; acc[3][1] += a3*wv.y; acc[3][2] += a3*wv.z; acc[3][3] += a3*wv.w;
        }
        __syncthreads();
    }
    #pragma unroll
    for (int i = 0; i < 4; ++i) {
        int m = m0 + 4*tr + i;
        #pragma unroll
        for (int j = 0; j < 4; ++j) {
            int n = 4*tc + j;
            if (n < N) C[(long long)m * N + n] = acc[i][j] + bias[n];
        }
    }
}

// ---------------------------------------------------------------------------
// CRF: forward logsumexp scan + log_z + gold score + loss, one block per b.
// ---------------------------------------------------------------------------
__global__ __launch_bounds__(1024) void crf_kernel(
    const float* __restrict__ feats,
    const float* __restrict__ trans,
    const int*   __restrict__ tokens,
    const int*   __restrict__ tags,
    const int*   __restrict__ lengths,
    float* __restrict__ out)
{
    const int b = blockIdx.x;
    const int tid = threadIdx.x;
    __shared__ float tr_s[KTAGS*KTAGS];
    __shared__ float score_s[KTAGS];
    __shared__ float emit_s[KTAGS];
    __shared__ float red_s[16];
    __shared__ float logz_s;

    tr_s[tid] = trans[tid];
    if (tid < KTAGS) score_s[tid] = (tid == START_TAG) ? 0.0f : NEGV;
    __syncthreads();

    const int i = tid >> 5, j = tid & 31;
    for (int t = 0; t < T_STEPS; ++t) {
        if (tid < KTAGS) emit_s[tid] = feats[((long long)t*BATCH + b)*KTAGS + tid];
        __syncthreads();
        float e = score_s[j] + tr_s[i*KTAGS + j];
        float m = e;
        m = fmaxf(m, __shfl_xor(m, 1));  m = fmaxf(m, __shfl_xor(m, 2));
        m = fmaxf(m, __shfl_xor(m, 4));  m = fmaxf(m, __shfl_xor(m, 8));
        m = fmaxf(m, __shfl_xor(m, 16));
        float p = __expf(e - m);
        p += __shfl_xor(p, 1); p += __shfl_xor(p, 2); p += __shfl_xor(p, 4);
        p += __shfl_xor(p, 8); p += __shfl_xor(p, 16);
        float nv = m + __logf(p) + emit_s[i];
        int msk = tokens[(long long)t*BATCH + b] > 0;
        __syncthreads();
        if (j == 0) score_s[i] = msk ? nv : score_s[i];
        __syncthreads();
    }

    if (tid < KTAGS) {
        float v = score_s[tid] + tr_s[END_TAG*KTAGS + tid];
        float m = v;
        m = fmaxf(m, __shfl_xor(m, 1));  m = fmaxf(m, __shfl_xor(m, 2));
        m = fmaxf(m, __shfl_xor(m, 4));  m = fmaxf(m, __shfl_xor(m, 8));
        m = fmaxf(m, __shfl_xor(m, 16));
        float p = __expf(v - m);
        p += __shfl_xor(p, 1); p += __shfl_xor(p, 2); p += __shfl_xor(p, 4);
        p += __shfl_xor(p, 8); p += __shfl_xor(p, 16);
        if (tid == 0) logz_s = m + __logf(p);
    }
    __syncthreads();

    float val = 0.0f;
    if (tid < T_STEPS) {
        int t = tid;
        int cur  = tags[(long long)t*BATCH + b];
        int prev = (t == 0) ? START_TAG : tags[(long long)(t-1)*BATCH + b];
        int msk  = tokens[(long long)t*BATCH + b] > 0;
        if (msk) val = tr_s[cur*KTAGS + prev]
                     + feats[((long long)t*BATCH + b)*KTAGS + cur];
    }
    val += __shfl_xor(val, 1);  val += __shfl_xor(val, 2);
    val += __shfl_xor(val, 4);  val += __shfl_xor(val, 8);
    val += __shfl_xor(val, 16); val += __shfl_xor(val, 32);
    int wave = tid >> 6, lane = tid & 63;
    if (lane == 0) red_s[wave] = val;
    __syncthreads();
    if (tid == 0) {
        float g = 0.0f;
        #pragma unroll
        for (int w = 0; w < 16; ++w) g += red_s[w];
        g += tr_s[END_TAG*KTAGS + tags[(long long)(T_STEPS-1)*BATCH + b]];
        atomicAdd(out, (logz_s - g) / (float)lengths[b]);
    }
}

// ---------------------------------------------------------------------------
extern "C" void kernel_launch(void* const* d_in, const int* in_sizes, int n_in,
                              void* d_out, int out_size, void* d_ws, size_t ws_size,
                              hipStream_t stream) {
    const int*   tokens  = (const int*)  d_in[0];
    const int*   tags    = (const int*)  d_in[1];
    const int*   lengths = (const int*)  d_in[2];
    const float* embed   = (const float*)d_in[3];
    const float* wih0    = (const float*)d_in[4];
    const float* whh0    = (const float*)d_in[5];
    const float* b0      = (const float*)d_in[6];
    const float* wih1    = (const float*)d_in[7];
    const float* whh1    = (const float*)d_in[8];
    const float* b1      = (const float*)d_in[9];
    const float* lin_w   = (const float*)d_in[10];
    const float* lin_b   = (const float*)d_in[11];
    const float* trans   = (const float*)d_in[12];

    // Workspace layout (total ~123.2 MiB footprint, unchanged).
    // Flags (64 KiB) and the 8-parity h-exchange buffers (1 MiB) live INSIDE
    // the feats buffer (2 MiB): feats is dead until gemm_feats runs (after
    // lstm_mfma completes), and gemm overwrites the whole 2 MiB.
    char* ws = (char*)d_ws;
    unsigned short* hs0   = (unsigned short*)(ws);                   // 33,554,432
    unsigned short* hs1   = (unsigned short*)(ws +  33554432ULL);    // 33,554,432
    unsigned short* embB  = (unsigned short*)(ws +  67108864ULL);    // 32,768,000
    unsigned short* wp0   = (unsigned short*)(ws +  99876864ULL);    //  8,388,608
    unsigned short* wp1   = (unsigned short*)(ws + 108265472ULL);    // 12,582,912
    float*          feats = (float*)        (ws + 120848384ULL);     //  2,097,152
    unsigned int*   flagsP = (unsigned int*)feats;                   // 65,536
    unsigned long long* hbufP = (unsigned long long*)((char*)feats + 65536); // 1,048,576

    float* out = (float*)d_out;

    init_zero<<<dim3(512), 256, 0, stream>>>(flagsP, hbufP, out);
    convert_embed<<<dim3(16000), 256, 0, stream>>>(embed, embB);
    pack_w<<<dim3(2048), 256, 0, stream>>>(wih0, whh0, 512,  wp0);
    pack_w<<<dim3(3072), 256, 0, stream>>>(wih1, whh1, 1024, wp1);

    lstm_mfma<<<dim3(NBLK), 256, 0, stream>>>(
        tokens, embB, wp0, wp1, b0, b1, hs0, hs1, hbufP, flagsP);

    gemm_feats<<<dim3(1, 256, 1), 256, 0, stream>>>(
        hs1, lin_w, lin_b, feats, T_STEPS*BATCH, KTAGS, 2*HID);

    crf_kernel<<<dim3(BATCH), 1024, 0, stream>>>(feats, trans, tokens, tags,
                                                 lengths, out);
}